// Round 1
// baseline (1029.821 us; speedup 1.0000x reference)
//
#include <hip/hip_runtime.h>
#include <hip/hip_bf16.h>

#define IN_CH 128
#define HID 64
#define HEADS 8
#define CPH 8          // channels per head
#define NEG 0.2f
#define EPS_SM 1e-16f

// ---------- helpers ----------

__device__ inline unsigned fenc(float f) {
    unsigned u = __float_as_uint(f);
    return (u & 0x80000000u) ? ~u : (u | 0x80000000u);
}
__device__ inline float fdec(unsigned k) {
    return (k & 0x80000000u) ? __uint_as_float(k & 0x7fffffffu)
                             : __uint_as_float(~k);
}

// edge fetch tolerant to int32 or int64 storage of edge_index [2, E]
__device__ inline void get_edge(const void* ei, int is64, long E, long e, int N,
                                int& s, int& d) {
    if (e >= E) { s = d = (int)(e - E); return; }   // appended self-loop
    if (is64) {
        const long long* p = (const long long*)ei;
        s = (int)p[e];
        d = (int)p[E + e];
    } else {
        const int* p = (const int*)ei;
        s = p[e];
        d = p[E + e];
    }
}

// ---------- kernels ----------

// Decide whether edge_index is stored as int64 (flag=1) or int32 (flag=0).
__global__ void detect_kernel(const void* ei, long E, int N, int* flag) {
    __shared__ int bad;
    if (threadIdx.x == 0) bad = 0;
    __syncthreads();
    const long long* p = (const long long*)ei;
    int n = (int)min((long)64, E);   // first n int64 entries (all within buffer)
    if ((int)threadIdx.x < n) {
        long long v = p[threadIdx.x];
        if (v < 0 || v >= (long long)N) atomicOr(&bad, 1);
    }
    __syncthreads();
    if (threadIdx.x == 0) *flag = bad ? 0 : 1;
}

// h1 = x @ W1 (N x 64), plus per-head attention dots a_src1/a_dst1 (N x 8).
// 64 lanes per node row; 4 nodes per 256-thread block.
__global__ __launch_bounds__(256) void gemm1_kernel(
    const float* __restrict__ x, const float* __restrict__ W1,
    const float* __restrict__ att_src, const float* __restrict__ att_dst,
    float* __restrict__ h1, float* __restrict__ a_src, float* __restrict__ a_dst,
    int N) {
    __shared__ float xs[4][IN_CH];
    int g = threadIdx.x >> 6;
    int lane = threadIdx.x & 63;
    long n = (long)blockIdx.x * 4 + g;
    bool active = n < N;
    long nn = active ? n : (long)(N - 1);

    // stage x row (one wave per row -> no barrier needed, wave-internal dep)
    xs[g][lane] = x[nn * IN_CH + lane];
    xs[g][lane + 64] = x[nn * IN_CH + 64 + lane];

    float acc = 0.f;
#pragma unroll 8
    for (int k = 0; k < IN_CH; ++k)
        acc += xs[g][k] * W1[(long)k * HID + lane];

    int h = lane >> 3, j = lane & 7;
    float ps = acc * att_src[h * CPH + j];
    float pd = acc * att_dst[h * CPH + j];
#pragma unroll
    for (int m = 1; m < 8; m <<= 1) {
        ps += __shfl_xor(ps, m);
        pd += __shfl_xor(pd, m);
    }
    if (active) {
        h1[nn * HID + lane] = acc;
        if (j == 0) {
            a_src[nn * HEADS + h] = ps;
            a_dst[nn * HEADS + h] = pd;
        }
    }
}

// zero/neg-inf init of all accumulators
__global__ void init_kernel(unsigned* amax1, float* denom1, float* out1,
                            unsigned* amax2, float* denom2, int N) {
    long i = (long)blockIdx.x * 256 + threadIdx.x;
    long n64 = (long)N * HID, n8 = (long)N * HEADS;
    if (i < n64) out1[i] = 0.f;
    if (i < n8) { amax1[i] = 0u; denom1[i] = 0.f; }
    if (i < N) { amax2[i] = 0u; denom2[i] = 0.f; }
}

// layer-1 segment max: one thread per edge, 8 heads each
__global__ void edge_max1_kernel(const void* ei, const int* flag,
                                 const float* __restrict__ a_src,
                                 const float* __restrict__ a_dst,
                                 unsigned* amax, long E, int N) {
    long e = (long)blockIdx.x * 256 + threadIdx.x;
    long ET = E + N;
    if (e >= ET) return;
    int s, d;
    get_edge(ei, *flag, E, e, N, s, d);
    const float4* as = (const float4*)(a_src + (long)s * HEADS);
    const float4* ad = (const float4*)(a_dst + (long)d * HEADS);
    float4 s0 = as[0], s1 = as[1], d0 = ad[0], d1 = ad[1];
    float r[8] = {s0.x + d0.x, s0.y + d0.y, s0.z + d0.z, s0.w + d0.w,
                  s1.x + d1.x, s1.y + d1.y, s1.z + d1.z, s1.w + d1.w};
#pragma unroll
    for (int h = 0; h < HEADS; ++h) {
        float v = r[h];
        v = v >= 0.f ? v : NEG * v;
        atomicMax(&amax[(long)d * HEADS + h], fenc(v));
    }
}

// layer-1 exp + denominator sum
__global__ void edge_expsum1_kernel(const void* ei, const int* flag,
                                    const float* __restrict__ a_src,
                                    const float* __restrict__ a_dst,
                                    const unsigned* __restrict__ amax,
                                    float* denom, long E, int N) {
    long e = (long)blockIdx.x * 256 + threadIdx.x;
    long ET = E + N;
    if (e >= ET) return;
    int s, d;
    get_edge(ei, *flag, E, e, N, s, d);
    const float4* as = (const float4*)(a_src + (long)s * HEADS);
    const float4* ad = (const float4*)(a_dst + (long)d * HEADS);
    float4 s0 = as[0], s1 = as[1], d0 = ad[0], d1 = ad[1];
    float r[8] = {s0.x + d0.x, s0.y + d0.y, s0.z + d0.z, s0.w + d0.w,
                  s1.x + d1.x, s1.y + d1.y, s1.z + d1.z, s1.w + d1.w};
#pragma unroll
    for (int h = 0; h < HEADS; ++h) {
        float v = r[h];
        v = v >= 0.f ? v : NEG * v;
        float m = fdec(amax[(long)d * HEADS + h]);
        atomicAdd(&denom[(long)d * HEADS + h], __expf(v - m));
    }
}

// layer-1 message scatter: 64 lanes per edge (one lane per hidden channel)
__global__ __launch_bounds__(256) void edge_msg1_kernel(
    const void* ei, const int* flag,
    const float* __restrict__ a_src, const float* __restrict__ a_dst,
    const unsigned* __restrict__ amax, const float* __restrict__ denom,
    const float* __restrict__ h1, float* out1, long E, int N) {
    long idx = (long)blockIdx.x * 256 + threadIdx.x;
    long e = idx >> 6;
    int lane = threadIdx.x & 63;
    if (e >= E + N) return;
    int s, d;
    get_edge(ei, *flag, E, e, N, s, d);
    int h = lane >> 3;
    float v = a_src[(long)s * HEADS + h] + a_dst[(long)d * HEADS + h];
    v = v >= 0.f ? v : NEG * v;
    float m = fdec(amax[(long)d * HEADS + h]);
    float den = denom[(long)d * HEADS + h];
    float alpha = __expf(v - m) / (den + EPS_SM);
    float msg = alpha * h1[(long)s * HID + lane];
    atomicAdd(&out1[(long)d * HID + lane], msg);
}

// layer-2 node prep: h2 = elu(out1+b1); hh = h2 @ W2 (64->8); attention dots;
// out2 := b2.  64 lanes per node, 4 nodes per block.
__global__ __launch_bounds__(256) void node2_kernel(
    const float* __restrict__ out1, const float* __restrict__ b1,
    const float* __restrict__ W2, const float* __restrict__ att_src2,
    const float* __restrict__ att_dst2, const float* __restrict__ b2,
    float* hh, float* a_src2, float* a_dst2, float* out2, int N) {
    int g = threadIdx.x >> 6;
    int lane = threadIdx.x & 63;
    long n = (long)blockIdx.x * 4 + g;
    bool active = n < N;
    long nn = active ? n : (long)(N - 1);

    float v = out1[nn * HID + lane] + b1[lane];
    v = v > 0.f ? v : expm1f(v);   // ELU

    const float4* wp = (const float4*)(W2 + (long)lane * CPH);
    float4 w0 = wp[0], w1 = wp[1];
    float w[8] = {w0.x, w0.y, w0.z, w0.w, w1.x, w1.y, w1.z, w1.w};

    float hhj = 0.f;
#pragma unroll
    for (int j = 0; j < CPH; ++j) {
        float p = v * w[j];
#pragma unroll
        for (int m = 1; m < 64; m <<= 1) p += __shfl_xor(p, m);
        if (lane == j) hhj = p;
    }
    float cs = (lane < CPH) ? hhj * att_src2[lane] : 0.f;
    float cd = (lane < CPH) ? hhj * att_dst2[lane] : 0.f;
#pragma unroll
    for (int m = 1; m < 8; m <<= 1) {
        cs += __shfl_xor(cs, m);
        cd += __shfl_xor(cd, m);
    }
    if (active) {
        if (lane < CPH) {
            hh[nn * CPH + lane] = hhj;
            out2[nn * CPH + lane] = b2[lane];
        }
        if (lane == 0) {
            a_src2[nn] = cs;
            a_dst2[nn] = cd;
        }
    }
}

// layer-2 segment max (1 head)
__global__ void edge_max2_kernel(const void* ei, const int* flag,
                                 const float* __restrict__ a_src,
                                 const float* __restrict__ a_dst,
                                 unsigned* amax, long E, int N) {
    long e = (long)blockIdx.x * 256 + threadIdx.x;
    if (e >= E + N) return;
    int s, d;
    get_edge(ei, *flag, E, e, N, s, d);
    float v = a_src[s] + a_dst[d];
    v = v >= 0.f ? v : NEG * v;
    atomicMax(&amax[d], fenc(v));
}

__global__ void edge_expsum2_kernel(const void* ei, const int* flag,
                                    const float* __restrict__ a_src,
                                    const float* __restrict__ a_dst,
                                    const unsigned* __restrict__ amax,
                                    float* denom, long E, int N) {
    long e = (long)blockIdx.x * 256 + threadIdx.x;
    if (e >= E + N) return;
    int s, d;
    get_edge(ei, *flag, E, e, N, s, d);
    float v = a_src[s] + a_dst[d];
    v = v >= 0.f ? v : NEG * v;
    float m = fdec(amax[d]);
    atomicAdd(&denom[d], __expf(v - m));
}

// layer-2 message scatter: 8 lanes per edge
__global__ void edge_msg2_kernel(const void* ei, const int* flag,
                                 const float* __restrict__ a_src,
                                 const float* __restrict__ a_dst,
                                 const unsigned* __restrict__ amax,
                                 const float* __restrict__ denom,
                                 const float* __restrict__ hh, float* out,
                                 long E, int N) {
    long idx = (long)blockIdx.x * 256 + threadIdx.x;
    long e = idx >> 3;
    int c = threadIdx.x & 7;
    if (e >= E + N) return;
    int s, d;
    get_edge(ei, *flag, E, e, N, s, d);
    float v = a_src[s] + a_dst[d];
    v = v >= 0.f ? v : NEG * v;
    float m = fdec(amax[d]);
    float den = denom[d];
    float alpha = __expf(v - m) / (den + EPS_SM);
    atomicAdd(&out[(long)d * CPH + c], alpha * hh[(long)s * CPH + c]);
}

// ---------- launcher ----------

extern "C" void kernel_launch(void* const* d_in, const int* in_sizes, int n_in,
                              void* d_out, int out_size, void* d_ws, size_t ws_size,
                              hipStream_t stream) {
    const float* x = (const float*)d_in[0];
    const void* ei = d_in[1];
    const float* W1 = (const float*)d_in[2];
    const float* att_src1 = (const float*)d_in[3];
    const float* att_dst1 = (const float*)d_in[4];
    const float* b1 = (const float*)d_in[5];
    const float* W2 = (const float*)d_in[6];
    const float* att_src2 = (const float*)d_in[7];
    const float* att_dst2 = (const float*)d_in[8];
    const float* b2 = (const float*)d_in[9];
    float* out = (float*)d_out;

    int N = in_sizes[0] / IN_CH;
    long E = (long)in_sizes[1] / 2;
    long ET = E + N;

    // workspace layout
    char* w = (char*)d_ws;
    int* flag = (int*)w;
    float* h1 = (float*)(w + 256);
    float* a_src1 = h1 + (long)N * HID;
    float* a_dst1 = a_src1 + (long)N * HEADS;
    unsigned* amax1 = (unsigned*)(a_dst1 + (long)N * HEADS);
    float* denom1 = (float*)(amax1 + (long)N * HEADS);
    float* out1 = denom1 + (long)N * HEADS;
    float* hh = out1 + (long)N * HID;
    float* a_src2 = hh + (long)N * CPH;
    float* a_dst2 = a_src2 + N;
    unsigned* amax2 = (unsigned*)(a_dst2 + N);
    float* denom2 = (float*)(amax2 + N);

    detect_kernel<<<1, 64, 0, stream>>>(ei, E, N, flag);

    gemm1_kernel<<<(N + 3) / 4, 256, 0, stream>>>(x, W1, att_src1, att_dst1,
                                                  h1, a_src1, a_dst1, N);

    long initN = (long)N * HID;
    init_kernel<<<(initN + 255) / 256, 256, 0, stream>>>(amax1, denom1, out1,
                                                         amax2, denom2, N);

    int ge = (int)((ET + 255) / 256);
    edge_max1_kernel<<<ge, 256, 0, stream>>>(ei, flag, a_src1, a_dst1, amax1, E, N);
    edge_expsum1_kernel<<<ge, 256, 0, stream>>>(ei, flag, a_src1, a_dst1, amax1,
                                                denom1, E, N);
    long t1 = ET * 64;
    edge_msg1_kernel<<<(int)((t1 + 255) / 256), 256, 0, stream>>>(
        ei, flag, a_src1, a_dst1, amax1, denom1, h1, out1, E, N);

    node2_kernel<<<(N + 3) / 4, 256, 0, stream>>>(out1, b1, W2, att_src2,
                                                  att_dst2, b2, hh, a_src2,
                                                  a_dst2, out, N);

    edge_max2_kernel<<<ge, 256, 0, stream>>>(ei, flag, a_src2, a_dst2, amax2, E, N);
    edge_expsum2_kernel<<<ge, 256, 0, stream>>>(ei, flag, a_src2, a_dst2, amax2,
                                                denom2, E, N);
    long t2 = ET * 8;
    edge_msg2_kernel<<<(int)((t2 + 255) / 256), 256, 0, stream>>>(
        ei, flag, a_src2, a_dst2, amax2, denom2, hh, out, E, N);
}

// Round 2
// 317.483 us; speedup vs baseline: 3.2437x; 3.2437x over previous
//
#include <hip/hip_runtime.h>
#include <hip/hip_bf16.h>

#define IN_CH 128
#define HID 64
#define HEADS 8
#define CPH 8          // channels per head
#define NEG 0.2f
#define EPS_SM 1e-16f
#define NINF -3.4e38f

// ---------- helpers ----------

// edge fetch tolerant to int32 or int64 storage of edge_index [2, E]
__device__ inline void get_edge(const void* ei, int is64, long E, long e, int N,
                                int& s, int& d) {
    if (e >= E) { s = d = (int)(e - E); return; }   // appended self-loop
    if (is64) {
        const long long* p = (const long long*)ei;
        s = (int)p[e];
        d = (int)p[E + e];
    } else {
        const int* p = (const int*)ei;
        s = p[e];
        d = p[E + e];
    }
}

// ---------- kernels ----------

// Decide whether edge_index is stored as int64 (flag=1) or int32 (flag=0).
__global__ void detect_kernel(const void* ei, long E, int N, int* flag) {
    __shared__ int bad;
    if (threadIdx.x == 0) bad = 0;
    __syncthreads();
    const long long* p = (const long long*)ei;
    int n = (int)min((long)64, E);
    if ((int)threadIdx.x < n) {
        long long v = p[threadIdx.x];
        if (v < 0 || v >= (long long)N) atomicOr(&bad, 1);
    }
    __syncthreads();
    if (threadIdx.x == 0) *flag = bad ? 0 : 1;
}

// h1 = x @ W1 (N x 64), plus per-head attention dots a_src1/a_dst1 (N x 8).
__global__ __launch_bounds__(256) void gemm1_kernel(
    const float* __restrict__ x, const float* __restrict__ W1,
    const float* __restrict__ att_src, const float* __restrict__ att_dst,
    float* __restrict__ h1, float* __restrict__ a_src, float* __restrict__ a_dst,
    int N) {
    __shared__ float xs[4][IN_CH];
    int g = threadIdx.x >> 6;
    int lane = threadIdx.x & 63;
    long n = (long)blockIdx.x * 4 + g;
    bool active = n < N;
    long nn = active ? n : (long)(N - 1);

    xs[g][lane] = x[nn * IN_CH + lane];
    xs[g][lane + 64] = x[nn * IN_CH + 64 + lane];

    float acc = 0.f;
#pragma unroll 8
    for (int k = 0; k < IN_CH; ++k)
        acc += xs[g][k] * W1[(long)k * HID + lane];

    int h = lane >> 3, j = lane & 7;
    float ps = acc * att_src[h * CPH + j];
    float pd = acc * att_dst[h * CPH + j];
#pragma unroll
    for (int m = 1; m < 8; m <<= 1) {
        ps += __shfl_xor(ps, m);
        pd += __shfl_xor(pd, m);
    }
    if (active) {
        h1[nn * HID + lane] = acc;
        if (j == 0) {
            a_src[nn * HEADS + h] = ps;
            a_dst[nn * HEADS + h] = pd;
        }
    }
}

__global__ void zero_deg_kernel(int* deg, int N) {
    int i = blockIdx.x * 256 + threadIdx.x;
    if (i < N) deg[i] = 0;
}

__global__ void hist_kernel(const void* ei, const int* flag, int* deg,
                            long E, int N) {
    long e = (long)blockIdx.x * 256 + threadIdx.x;
    if (e >= E + N) return;
    int s, d;
    get_edge(ei, *flag, E, e, N, s, d);
    atomicAdd(&deg[d], 1);
}

// exclusive block scan of deg -> start, block totals -> bsum
__global__ void scan1_kernel(const int* deg, int* start, int* bsum, int N) {
    __shared__ int sh[256];
    int t = threadIdx.x;
    int i = blockIdx.x * 256 + t;
    int v = (i < N) ? deg[i] : 0;
    sh[t] = v;
    __syncthreads();
    for (int o = 1; o < 256; o <<= 1) {
        int x = (t >= o) ? sh[t - o] : 0;
        __syncthreads();
        sh[t] += x;
        __syncthreads();
    }
    if (i < N) start[i] = sh[t] - v;
    if (t == 255) bsum[blockIdx.x] = sh[255];
}

// single-block exclusive scan of bsum (any nb, chunked by 256)
__global__ void scan2_kernel(int* bsum, int nb) {
    __shared__ int sh[256];
    __shared__ int carry;
    int t = threadIdx.x;
    if (t == 0) carry = 0;
    __syncthreads();
    for (int base = 0; base < nb; base += 256) {
        int v = (base + t < nb) ? bsum[base + t] : 0;
        sh[t] = v;
        __syncthreads();
        for (int o = 1; o < 256; o <<= 1) {
            int x = (t >= o) ? sh[t - o] : 0;
            __syncthreads();
            sh[t] += x;
            __syncthreads();
        }
        if (base + t < nb) bsum[base + t] = sh[t] - v + carry;
        __syncthreads();
        if (t == 0) carry += sh[255];
        __syncthreads();
    }
}

__global__ void scan3_kernel(int* start, const int* bsum, int N) {
    int i = blockIdx.x * 256 + threadIdx.x;
    if (i < N) start[i] += bsum[blockIdx.x];
}

// scatter src ids into CSR; start[d] mutates from excl-begin to excl-end
__global__ void scatter_kernel(const void* ei, const int* flag, int* start,
                               int* csr_src, long E, int N) {
    long e = (long)blockIdx.x * 256 + threadIdx.x;
    if (e >= E + N) return;
    int s, d;
    get_edge(ei, *flag, E, e, N, s, d);
    int pos = atomicAdd(&start[d], 1);
    csr_src[pos] = s;
}

// layer-1 per-node softmax + aggregation, one wave per node
__global__ __launch_bounds__(256) void agg1_kernel(
    const int* __restrict__ start, const int* __restrict__ csr_src,
    const float* __restrict__ a_src, const float* __restrict__ a_dst,
    const float* __restrict__ h1, float* __restrict__ out1, int N) {
    int lane = threadIdx.x & 63;
    long d = (long)blockIdx.x * 4 + (threadIdx.x >> 6);
    if (d >= N) return;
    int begin = (d == 0) ? 0 : start[d - 1];
    int end = start[d];

    // phase A: lane = eslot*8 + head
    int i = lane >> 3, h = lane & 7;
    float adst = a_dst[d * HEADS + h];
    float mx = NINF;
    for (int k = begin + i; k < end; k += 8) {
        int s = csr_src[k];
        float v = a_src[(long)s * HEADS + h] + adst;
        v = v >= 0.f ? v : NEG * v;
        mx = fmaxf(mx, v);
    }
    mx = fmaxf(mx, __shfl_xor(mx, 8));
    mx = fmaxf(mx, __shfl_xor(mx, 16));
    mx = fmaxf(mx, __shfl_xor(mx, 32));
    float den = 0.f;
    for (int k = begin + i; k < end; k += 8) {
        int s = csr_src[k];
        float v = a_src[(long)s * HEADS + h] + adst;
        v = v >= 0.f ? v : NEG * v;
        den += __expf(v - mx);
    }
    den += __shfl_xor(den, 8);
    den += __shfl_xor(den, 16);
    den += __shfl_xor(den, 32);

    // phase B: lane owns channel `lane`, head = lane>>3
    int hb = lane >> 3;
    float mxb = __shfl(mx, hb);      // lane hb holds head hb's reduction
    float denb = __shfl(den, hb);
    float adstb = a_dst[d * HEADS + hb];
    float inv = 1.f / (denb + EPS_SM);
    float acc = 0.f;
    for (int k = begin; k < end; ++k) {
        int s = csr_src[k];
        float v = a_src[(long)s * HEADS + hb] + adstb;
        v = v >= 0.f ? v : NEG * v;
        acc += __expf(v - mxb) * h1[(long)s * HID + lane];
    }
    out1[d * HID + lane] = acc * inv;
}

// layer-2 node prep: h2 = elu(out1+b1); hh = h2 @ W2 (64->8); attention dots
__global__ __launch_bounds__(256) void node2_kernel(
    const float* __restrict__ out1, const float* __restrict__ b1,
    const float* __restrict__ W2, const float* __restrict__ att_src2,
    const float* __restrict__ att_dst2,
    float* hh, float* a_src2, float* a_dst2, int N) {
    int g = threadIdx.x >> 6;
    int lane = threadIdx.x & 63;
    long n = (long)blockIdx.x * 4 + g;
    bool active = n < N;
    long nn = active ? n : (long)(N - 1);

    float v = out1[nn * HID + lane] + b1[lane];
    v = v > 0.f ? v : expm1f(v);   // ELU

    const float4* wp = (const float4*)(W2 + (long)lane * CPH);
    float4 w0 = wp[0], w1 = wp[1];
    float w[8] = {w0.x, w0.y, w0.z, w0.w, w1.x, w1.y, w1.z, w1.w};

    float hhj = 0.f;
#pragma unroll
    for (int j = 0; j < CPH; ++j) {
        float p = v * w[j];
#pragma unroll
        for (int m = 1; m < 64; m <<= 1) p += __shfl_xor(p, m);
        if (lane == j) hhj = p;
    }
    float cs = (lane < CPH) ? hhj * att_src2[lane] : 0.f;
    float cd = (lane < CPH) ? hhj * att_dst2[lane] : 0.f;
#pragma unroll
    for (int m = 1; m < 8; m <<= 1) {
        cs += __shfl_xor(cs, m);
        cd += __shfl_xor(cd, m);
    }
    if (active) {
        if (lane < CPH) hh[nn * CPH + lane] = hhj;
        if (lane == 0) {
            a_src2[nn] = cs;
            a_dst2[nn] = cd;
        }
    }
}

// layer-2 per-node softmax + aggregation, 8 lanes per node
__global__ __launch_bounds__(256) void agg2_kernel(
    const int* __restrict__ start, const int* __restrict__ csr_src,
    const float* __restrict__ a_src, const float* __restrict__ a_dst,
    const float* __restrict__ hh, const float* __restrict__ b2,
    float* __restrict__ out, int N) {
    int c = threadIdx.x & 7;
    long d = (long)blockIdx.x * 32 + (threadIdx.x >> 3);
    if (d >= N) return;
    int begin = (d == 0) ? 0 : start[d - 1];
    int end = start[d];
    float adst = a_dst[d];
    float mx = NINF;
    for (int k = begin + c; k < end; k += 8) {
        float v = a_src[csr_src[k]] + adst;
        v = v >= 0.f ? v : NEG * v;
        mx = fmaxf(mx, v);
    }
    mx = fmaxf(mx, __shfl_xor(mx, 1));
    mx = fmaxf(mx, __shfl_xor(mx, 2));
    mx = fmaxf(mx, __shfl_xor(mx, 4));
    float den = 0.f;
    for (int k = begin + c; k < end; k += 8) {
        float v = a_src[csr_src[k]] + adst;
        v = v >= 0.f ? v : NEG * v;
        den += __expf(v - mx);
    }
    den += __shfl_xor(den, 1);
    den += __shfl_xor(den, 2);
    den += __shfl_xor(den, 4);
    float inv = 1.f / (den + EPS_SM);
    float acc = 0.f;
    for (int k = begin; k < end; ++k) {
        int s = csr_src[k];
        float v = a_src[s] + adst;
        v = v >= 0.f ? v : NEG * v;
        acc += __expf(v - mx) * hh[(long)s * CPH + c];
    }
    out[d * CPH + c] = acc * inv + b2[c];
}

// ---------- launcher ----------

extern "C" void kernel_launch(void* const* d_in, const int* in_sizes, int n_in,
                              void* d_out, int out_size, void* d_ws, size_t ws_size,
                              hipStream_t stream) {
    const float* x = (const float*)d_in[0];
    const void* ei = d_in[1];
    const float* W1 = (const float*)d_in[2];
    const float* att_src1 = (const float*)d_in[3];
    const float* att_dst1 = (const float*)d_in[4];
    const float* b1 = (const float*)d_in[5];
    const float* W2 = (const float*)d_in[6];
    const float* att_src2 = (const float*)d_in[7];
    const float* att_dst2 = (const float*)d_in[8];
    const float* b2 = (const float*)d_in[9];
    float* out = (float*)d_out;

    int N = in_sizes[0] / IN_CH;
    long E = (long)in_sizes[1] / 2;
    long ET = E + N;

    // workspace layout
    char* w = (char*)d_ws;
    int* flag = (int*)w;
    float* h1 = (float*)(w + 256);
    float* a_src1 = h1 + (long)N * HID;
    float* a_dst1 = a_src1 + (long)N * HEADS;
    float* out1 = a_dst1 + (long)N * HEADS;
    float* hh = out1 + (long)N * HID;
    float* a_src2 = hh + (long)N * CPH;
    float* a_dst2 = a_src2 + N;
    int* deg = (int*)(a_dst2 + N);
    int* start = deg + N;
    int* bsum = start + N;
    int* csr_src = bsum + 1024;

    int nb = (N + 255) / 256;
    int ge = (int)((ET + 255) / 256);

    detect_kernel<<<1, 64, 0, stream>>>(ei, E, N, flag);

    gemm1_kernel<<<(N + 3) / 4, 256, 0, stream>>>(x, W1, att_src1, att_dst1,
                                                  h1, a_src1, a_dst1, N);

    zero_deg_kernel<<<nb, 256, 0, stream>>>(deg, N);
    hist_kernel<<<ge, 256, 0, stream>>>(ei, flag, deg, E, N);
    scan1_kernel<<<nb, 256, 0, stream>>>(deg, start, bsum, N);
    scan2_kernel<<<1, 256, 0, stream>>>(bsum, nb);
    scan3_kernel<<<nb, 256, 0, stream>>>(start, bsum, N);
    scatter_kernel<<<ge, 256, 0, stream>>>(ei, flag, start, csr_src, E, N);

    agg1_kernel<<<(N + 3) / 4, 256, 0, stream>>>(start, csr_src, a_src1,
                                                 a_dst1, h1, out1, N);

    node2_kernel<<<(N + 3) / 4, 256, 0, stream>>>(out1, b1, W2, att_src2,
                                                  att_dst2, hh, a_src2,
                                                  a_dst2, N);

    agg2_kernel<<<(N + 31) / 32, 256, 0, stream>>>(start, csr_src, a_src2,
                                                   a_dst2, hh, b2, out, N);
}

// Round 3
// 289.378 us; speedup vs baseline: 3.5587x; 1.0971x over previous
//
#include <hip/hip_runtime.h>
#include <hip/hip_fp16.h>

#define IN_CH 128
#define HID 64
#define HEADS 8
#define CPH 8          // channels per head
#define NEG 0.2f
#define EPS_SM 1e-16f
#define NINF -3.4e38f

// ---------- helpers ----------

// edge fetch tolerant to int32 or int64 storage of edge_index [2, E]
__device__ inline void get_edge(const void* ei, int is64, long E, long e, int N,
                                int& s, int& d) {
    if (e >= E) { s = d = (int)(e - E); return; }   // appended self-loop
    if (is64) {
        const long long* p = (const long long*)ei;
        s = (int)p[e];
        d = (int)p[E + e];
    } else {
        const int* p = (const int*)ei;
        s = p[e];
        d = p[E + e];
    }
}

// ---------- kernels ----------

// Decide whether edge_index is stored as int64 (flag=1) or int32 (flag=0).
__global__ void detect_kernel(const void* ei, long E, int N, int* flag) {
    __shared__ int bad;
    if (threadIdx.x == 0) bad = 0;
    __syncthreads();
    const long long* p = (const long long*)ei;
    int n = (int)min((long)64, E);
    if ((int)threadIdx.x < n) {
        long long v = p[threadIdx.x];
        if (v < 0 || v >= (long long)N) atomicOr(&bad, 1);
    }
    __syncthreads();
    if (threadIdx.x == 0) *flag = bad ? 0 : 1;
}

// h1 = x @ W1 (N x 64) in fp16, plus attention dots a_src1/a_dst1 (N x 8).
__global__ __launch_bounds__(256) void gemm1_kernel(
    const float* __restrict__ x, const float* __restrict__ W1,
    const float* __restrict__ att_src, const float* __restrict__ att_dst,
    __half* __restrict__ h1, float* __restrict__ a_src, float* __restrict__ a_dst,
    int N) {
    __shared__ float xs[4][IN_CH];
    int g = threadIdx.x >> 6;
    int lane = threadIdx.x & 63;
    long n = (long)blockIdx.x * 4 + g;
    bool active = n < N;
    long nn = active ? n : (long)(N - 1);

    xs[g][lane] = x[nn * IN_CH + lane];
    xs[g][lane + 64] = x[nn * IN_CH + 64 + lane];

    float acc = 0.f;
#pragma unroll 8
    for (int k = 0; k < IN_CH; ++k)
        acc += xs[g][k] * W1[(long)k * HID + lane];

    int h = lane >> 3, j = lane & 7;
    float ps = acc * att_src[h * CPH + j];
    float pd = acc * att_dst[h * CPH + j];
#pragma unroll
    for (int m = 1; m < 8; m <<= 1) {
        ps += __shfl_xor(ps, m);
        pd += __shfl_xor(pd, m);
    }
    if (active) {
        h1[nn * HID + lane] = __float2half(acc);
        if (j == 0) {
            a_src[nn * HEADS + h] = ps;
            a_dst[nn * HEADS + h] = pd;
        }
    }
}

__global__ void zero_deg_kernel(int* deg, int N) {
    int i = blockIdx.x * 256 + threadIdx.x;
    if (i < N) deg[i] = 0;
}

__global__ void hist_kernel(const void* ei, const int* flag, int* deg,
                            long E, int N) {
    long e = (long)blockIdx.x * 256 + threadIdx.x;
    if (e >= E + N) return;
    int s, d;
    get_edge(ei, *flag, E, e, N, s, d);
    atomicAdd(&deg[d], 1);
}

// exclusive block scan of deg -> start, block totals -> bsum
__global__ void scan1_kernel(const int* deg, int* start, int* bsum, int N) {
    __shared__ int sh[256];
    int t = threadIdx.x;
    int i = blockIdx.x * 256 + t;
    int v = (i < N) ? deg[i] : 0;
    sh[t] = v;
    __syncthreads();
    for (int o = 1; o < 256; o <<= 1) {
        int x = (t >= o) ? sh[t - o] : 0;
        __syncthreads();
        sh[t] += x;
        __syncthreads();
    }
    if (i < N) start[i] = sh[t] - v;
    if (t == 255) bsum[blockIdx.x] = sh[255];
}

// single-block exclusive scan of bsum (any nb, chunked by 256)
__global__ void scan2_kernel(int* bsum, int nb) {
    __shared__ int sh[256];
    __shared__ int carry;
    int t = threadIdx.x;
    if (t == 0) carry = 0;
    __syncthreads();
    for (int base = 0; base < nb; base += 256) {
        int v = (base + t < nb) ? bsum[base + t] : 0;
        sh[t] = v;
        __syncthreads();
        for (int o = 1; o < 256; o <<= 1) {
            int x = (t >= o) ? sh[t - o] : 0;
            __syncthreads();
            sh[t] += x;
            __syncthreads();
        }
        if (base + t < nb) bsum[base + t] = sh[t] - v + carry;
        __syncthreads();
        if (t == 0) carry += sh[255];
        __syncthreads();
    }
}

__global__ void scan3_kernel(int* start, const int* bsum, int N) {
    int i = blockIdx.x * 256 + threadIdx.x;
    if (i < N) start[i] += bsum[blockIdx.x];
}

// scatter src ids into CSR; start[d] mutates from excl-begin to excl-end
__global__ void scatter_kernel(const void* ei, const int* flag, int* start,
                               int* csr_src, long E, int N) {
    long e = (long)blockIdx.x * 256 + threadIdx.x;
    if (e >= E + N) return;
    int s, d;
    get_edge(ei, *flag, E, e, N, s, d);
    int pos = atomicAdd(&start[d], 1);
    csr_src[pos] = s;
}

// layer-1 softmax + aggregation + fused layer-2 node prep, one wave per node.
// Epilogue: h2 = elu(agg + b1); hh = h2 @ W2 (fp16); a_src2/a_dst2 dots.
__global__ __launch_bounds__(256) void agg1_kernel(
    const int* __restrict__ start, const int* __restrict__ csr_src,
    const float* __restrict__ a_src, const float* __restrict__ a_dst,
    const __half* __restrict__ h1,
    const float* __restrict__ b1, const float* __restrict__ W2,
    const float* __restrict__ att_src2, const float* __restrict__ att_dst2,
    __half* __restrict__ hh, float* __restrict__ a_src2,
    float* __restrict__ a_dst2, int N) {
    int lane = threadIdx.x & 63;
    long d = (long)blockIdx.x * 4 + (threadIdx.x >> 6);
    if (d >= N) return;
    int begin = (d == 0) ? 0 : start[d - 1];
    int end = start[d];

    // phase A: lane = eslot*8 + head -> per-head max & denom
    int i = lane >> 3, h = lane & 7;
    float adst = a_dst[d * HEADS + h];
    float mx = NINF;
    for (int k = begin + i; k < end; k += 8) {
        int s = csr_src[k];
        float v = a_src[(long)s * HEADS + h] + adst;
        v = v >= 0.f ? v : NEG * v;
        mx = fmaxf(mx, v);
    }
    mx = fmaxf(mx, __shfl_xor(mx, 8));
    mx = fmaxf(mx, __shfl_xor(mx, 16));
    mx = fmaxf(mx, __shfl_xor(mx, 32));
    float den = 0.f;
    for (int k = begin + i; k < end; k += 8) {
        int s = csr_src[k];
        float v = a_src[(long)s * HEADS + h] + adst;
        v = v >= 0.f ? v : NEG * v;
        den += __expf(v - mx);
    }
    den += __shfl_xor(den, 8);
    den += __shfl_xor(den, 16);
    den += __shfl_xor(den, 32);

    // phase B: lane owns channel `lane`, head = lane>>3
    int hb = lane >> 3;
    float mxb = __shfl(mx, hb);
    float denb = __shfl(den, hb);
    float adstb = a_dst[d * HEADS + hb];
    float inv = 1.f / (denb + EPS_SM);
    float acc = 0.f;
    for (int k = begin; k < end; ++k) {
        int s = csr_src[k];
        float v = a_src[(long)s * HEADS + hb] + adstb;
        v = v >= 0.f ? v : NEG * v;
        acc += __expf(v - mxb) * __half2float(h1[(long)s * HID + lane]);
    }

    // fused node2 epilogue
    float v = acc * inv + b1[lane];
    v = v > 0.f ? v : expm1f(v);   // ELU

    const float4* wp = (const float4*)(W2 + (long)lane * CPH);
    float4 w0 = wp[0], w1 = wp[1];
    float wv[8] = {w0.x, w0.y, w0.z, w0.w, w1.x, w1.y, w1.z, w1.w};

    float hhj = 0.f;
#pragma unroll
    for (int j = 0; j < CPH; ++j) {
        float p = v * wv[j];
#pragma unroll
        for (int m = 1; m < 64; m <<= 1) p += __shfl_xor(p, m);
        if (lane == j) hhj = p;
    }
    float cs = (lane < CPH) ? hhj * att_src2[lane] : 0.f;
    float cd = (lane < CPH) ? hhj * att_dst2[lane] : 0.f;
#pragma unroll
    for (int m = 1; m < 8; m <<= 1) {
        cs += __shfl_xor(cs, m);
        cd += __shfl_xor(cd, m);
    }
    if (lane < CPH) hh[d * CPH + lane] = __float2half(hhj);
    if (lane == 0) {
        a_src2[d] = cs;
        a_dst2[d] = cd;
    }
}

// layer-2 per-node softmax + aggregation, 8 lanes per node
__global__ __launch_bounds__(256) void agg2_kernel(
    const int* __restrict__ start, const int* __restrict__ csr_src,
    const float* __restrict__ a_src, const float* __restrict__ a_dst,
    const __half* __restrict__ hh, const float* __restrict__ b2,
    float* __restrict__ out, int N) {
    int c = threadIdx.x & 7;
    long d = (long)blockIdx.x * 32 + (threadIdx.x >> 3);
    if (d >= N) return;
    int begin = (d == 0) ? 0 : start[d - 1];
    int end = start[d];
    float adst = a_dst[d];
    float mx = NINF;
    for (int k = begin + c; k < end; k += 8) {
        float v = a_src[csr_src[k]] + adst;
        v = v >= 0.f ? v : NEG * v;
        mx = fmaxf(mx, v);
    }
    mx = fmaxf(mx, __shfl_xor(mx, 1));
    mx = fmaxf(mx, __shfl_xor(mx, 2));
    mx = fmaxf(mx, __shfl_xor(mx, 4));
    float den = 0.f;
    for (int k = begin + c; k < end; k += 8) {
        float v = a_src[csr_src[k]] + adst;
        v = v >= 0.f ? v : NEG * v;
        den += __expf(v - mx);
    }
    den += __shfl_xor(den, 1);
    den += __shfl_xor(den, 2);
    den += __shfl_xor(den, 4);
    float inv = 1.f / (den + EPS_SM);
    float acc = 0.f;
    for (int k = begin; k < end; ++k) {
        int s = csr_src[k];
        float v = a_src[s] + adst;
        v = v >= 0.f ? v : NEG * v;
        acc += __expf(v - mx) * __half2float(hh[(long)s * CPH + c]);
    }
    out[d * CPH + c] = acc * inv + b2[c];
}

// ---------- launcher ----------

extern "C" void kernel_launch(void* const* d_in, const int* in_sizes, int n_in,
                              void* d_out, int out_size, void* d_ws, size_t ws_size,
                              hipStream_t stream) {
    const float* x = (const float*)d_in[0];
    const void* ei = d_in[1];
    const float* W1 = (const float*)d_in[2];
    const float* att_src1 = (const float*)d_in[3];
    const float* att_dst1 = (const float*)d_in[4];
    const float* b1 = (const float*)d_in[5];
    const float* W2 = (const float*)d_in[6];
    const float* att_src2 = (const float*)d_in[7];
    const float* att_dst2 = (const float*)d_in[8];
    const float* b2 = (const float*)d_in[9];
    float* out = (float*)d_out;

    int N = in_sizes[0] / IN_CH;
    long E = (long)in_sizes[1] / 2;
    long ET = E + N;

    // workspace layout (byte offsets, 256-aligned blocks)
    char* w = (char*)d_ws;
    size_t off = 256;
    auto alloc = [&](size_t bytes) {
        size_t o = off;
        off += (bytes + 255) & ~(size_t)255;
        return (void*)(w + o);
    };
    int* flag = (int*)w;
    __half* h1 = (__half*)alloc((size_t)N * HID * 2);
    float* a_src1 = (float*)alloc((size_t)N * HEADS * 4);
    float* a_dst1 = (float*)alloc((size_t)N * HEADS * 4);
    __half* hh = (__half*)alloc((size_t)N * CPH * 2);
    float* a_src2 = (float*)alloc((size_t)N * 4);
    float* a_dst2 = (float*)alloc((size_t)N * 4);
    int* deg = (int*)alloc((size_t)N * 4);
    int* start = (int*)alloc((size_t)N * 4);
    int* bsum = (int*)alloc(1024 * 4);
    int* csr_src = (int*)alloc((size_t)ET * 4);

    int nb = (N + 255) / 256;
    int ge = (int)((ET + 255) / 256);

    detect_kernel<<<1, 64, 0, stream>>>(ei, E, N, flag);

    gemm1_kernel<<<(N + 3) / 4, 256, 0, stream>>>(x, W1, att_src1, att_dst1,
                                                  h1, a_src1, a_dst1, N);

    zero_deg_kernel<<<nb, 256, 0, stream>>>(deg, N);
    hist_kernel<<<ge, 256, 0, stream>>>(ei, flag, deg, E, N);
    scan1_kernel<<<nb, 256, 0, stream>>>(deg, start, bsum, N);
    scan2_kernel<<<1, 256, 0, stream>>>(bsum, nb);
    scan3_kernel<<<nb, 256, 0, stream>>>(start, bsum, N);
    scatter_kernel<<<ge, 256, 0, stream>>>(ei, flag, start, csr_src, E, N);

    agg1_kernel<<<(N + 3) / 4, 256, 0, stream>>>(start, csr_src, a_src1,
                                                 a_dst1, h1, b1, W2, att_src2,
                                                 att_dst2, hh, a_src2, a_dst2, N);

    agg2_kernel<<<(N + 31) / 32, 256, 0, stream>>>(start, csr_src, a_src2,
                                                   a_dst2, hh, b2, out, N);
}

// Round 4
// 216.997 us; speedup vs baseline: 4.7458x; 1.3336x over previous
//
#include <hip/hip_runtime.h>
#include <hip/hip_fp16.h>

#define IN_CH 128
#define HID 64
#define HEADS 8
#define CPH 8          // channels per head
#define NEG 0.2f
#define EPS_SM 1e-16f

// ---------- helpers ----------

// edge fetch tolerant to int32 or int64 storage of edge_index [2, E]
__device__ inline void get_edge(const void* ei, int is64, long E, long e, int N,
                                int& s, int& d) {
    if (e >= E) { s = d = (int)(e - E); return; }   // appended self-loop
    if (is64) {
        const long long* p = (const long long*)ei;
        s = (int)p[e];
        d = (int)p[E + e];
    } else {
        const int* p = (const int*)ei;
        s = p[e];
        d = p[E + e];
    }
}

// ---------- kernels ----------

// Decide whether edge_index is stored as int64 (flag=1) or int32 (flag=0).
__global__ void detect_kernel(const void* ei, long E, int N, int* flag) {
    __shared__ int bad;
    if (threadIdx.x == 0) bad = 0;
    __syncthreads();
    const long long* p = (const long long*)ei;
    int n = (int)min((long)64, E);
    if ((int)threadIdx.x < n) {
        long long v = p[threadIdx.x];
        if (v < 0 || v >= (long long)N) atomicOr(&bad, 1);
    }
    __syncthreads();
    if (threadIdx.x == 0) *flag = bad ? 0 : 1;
}

// h1 = x @ W1 (N x 64) in fp16, plus attention dots a_src1/a_dst1 (N x 8).
__global__ __launch_bounds__(256) void gemm1_kernel(
    const float* __restrict__ x, const float* __restrict__ W1,
    const float* __restrict__ att_src, const float* __restrict__ att_dst,
    __half* __restrict__ h1, float* __restrict__ a_src, float* __restrict__ a_dst,
    int N) {
    __shared__ float xs[4][IN_CH];
    int g = threadIdx.x >> 6;
    int lane = threadIdx.x & 63;
    long n = (long)blockIdx.x * 4 + g;
    bool active = n < N;
    long nn = active ? n : (long)(N - 1);

    xs[g][lane] = x[nn * IN_CH + lane];
    xs[g][lane + 64] = x[nn * IN_CH + 64 + lane];

    float a0 = 0.f, a1 = 0.f, a2 = 0.f, a3 = 0.f;
#pragma unroll
    for (int k = 0; k < IN_CH; k += 4) {
        a0 += xs[g][k]     * W1[(long)k * HID + lane];
        a1 += xs[g][k + 1] * W1[(long)(k + 1) * HID + lane];
        a2 += xs[g][k + 2] * W1[(long)(k + 2) * HID + lane];
        a3 += xs[g][k + 3] * W1[(long)(k + 3) * HID + lane];
    }
    float acc = (a0 + a1) + (a2 + a3);

    int h = lane >> 3, j = lane & 7;
    float ps = acc * att_src[h * CPH + j];
    float pd = acc * att_dst[h * CPH + j];
#pragma unroll
    for (int m = 1; m < 8; m <<= 1) {
        ps += __shfl_xor(ps, m);
        pd += __shfl_xor(pd, m);
    }
    if (active) {
        h1[nn * HID + lane] = __float2half(acc);
        if (j == 0) {
            a_src[nn * HEADS + h] = ps;
            a_dst[nn * HEADS + h] = pd;
        }
    }
}

__global__ void zero_deg_kernel(int* deg, int N) {
    int i = blockIdx.x * 256 + threadIdx.x;
    if (i < N) deg[i] = 0;
}

__global__ void hist_kernel(const void* ei, const int* flag, int* deg,
                            long E, int N) {
    long e = (long)blockIdx.x * 256 + threadIdx.x;
    if (e >= E + N) return;
    int s, d;
    get_edge(ei, *flag, E, e, N, s, d);
    atomicAdd(&deg[d], 1);
}

// exclusive block scan of deg -> start, block totals -> bsum
__global__ void scan1_kernel(const int* deg, int* start, int* bsum, int N) {
    __shared__ int sh[256];
    int t = threadIdx.x;
    int i = blockIdx.x * 256 + t;
    int v = (i < N) ? deg[i] : 0;
    sh[t] = v;
    __syncthreads();
    for (int o = 1; o < 256; o <<= 1) {
        int x = (t >= o) ? sh[t - o] : 0;
        __syncthreads();
        sh[t] += x;
        __syncthreads();
    }
    if (i < N) start[i] = sh[t] - v;
    if (t == 255) bsum[blockIdx.x] = sh[255];
}

// single-block exclusive scan of bsum (any nb, chunked by 256)
__global__ void scan2_kernel(int* bsum, int nb) {
    __shared__ int sh[256];
    __shared__ int carry;
    int t = threadIdx.x;
    if (t == 0) carry = 0;
    __syncthreads();
    for (int base = 0; base < nb; base += 256) {
        int v = (base + t < nb) ? bsum[base + t] : 0;
        sh[t] = v;
        __syncthreads();
        for (int o = 1; o < 256; o <<= 1) {
            int x = (t >= o) ? sh[t - o] : 0;
            __syncthreads();
            sh[t] += x;
            __syncthreads();
        }
        if (base + t < nb) bsum[base + t] = sh[t] - v + carry;
        __syncthreads();
        if (t == 0) carry += sh[255];
        __syncthreads();
    }
}

__global__ void scan3_kernel(int* start, const int* bsum, int N) {
    int i = blockIdx.x * 256 + threadIdx.x;
    if (i < N) start[i] += bsum[blockIdx.x];
}

// scatter src ids into CSR; start[d] mutates from excl-begin to excl-end
__global__ void scatter_kernel(const void* ei, const int* flag, int* start,
                               int* csr_src, long E, int N) {
    long e = (long)blockIdx.x * 256 + threadIdx.x;
    if (e >= E + N) return;
    int s, d;
    get_edge(ei, *flag, E, e, N, s, d);
    int pos = atomicAdd(&start[d], 1);
    csr_src[pos] = s;
}

// layer-1 single-pass softmax-aggregation + fused layer-2 node prep.
// One wave per node. No max-subtraction (logits are O(±6), fp32-safe):
//   acc_c = sum_e exp(v_eh) * h1[s_e][c],  den_h = sum_e exp(v_eh),
//   out_c = acc_c / den_h.
// Chunk of 8 edges: lane = eslot*8 + head computes one exp; broadcast via shfl.
__global__ __launch_bounds__(256) void agg1_kernel(
    const int* __restrict__ start, const int* __restrict__ csr_src,
    const float* __restrict__ a_src, const float* __restrict__ a_dst,
    const __half* __restrict__ h1,
    const float* __restrict__ b1, const float* __restrict__ W2,
    const float* __restrict__ att_src2, const float* __restrict__ att_dst2,
    __half* __restrict__ hh, float* __restrict__ a_src2,
    float* __restrict__ a_dst2, int N) {
    int lane = threadIdx.x & 63;
    long d = (long)blockIdx.x * 4 + (threadIdx.x >> 6);
    if (d >= N) return;
    int begin = (d == 0) ? 0 : start[d - 1];
    int end = start[d];

    int eslot = lane >> 3, h = lane & 7;   // chunk layout
    int hb = lane >> 3;                    // head owning channel `lane`
    float adst = a_dst[d * HEADS + h];

    float den = 0.f, acc = 0.f;
    for (int base = begin; base < end; base += 8) {
        int k = base + eslot;
        int sv = 0;
        float ev = 0.f;
        if (k < end) {
            sv = csr_src[k];
            float v = a_src[(long)sv * HEADS + h] + adst;
            v = v >= 0.f ? v : NEG * v;
            ev = __expf(v);
        }
        den += ev;
#pragma unroll
        for (int e = 0; e < 8; ++e) {
            float aE = __shfl(ev, e * 8 + hb);
            int sE = __shfl(sv, e * 8);
            acc += aE * __half2float(h1[(long)sE * HID + lane]);
        }
    }
    // reduce den over eslots (lane bits 3..5); result per head = lane&7
    den += __shfl_xor(den, 8);
    den += __shfl_xor(den, 16);
    den += __shfl_xor(den, 32);
    float denb = __shfl(den, hb);          // den for head hb
    float inv = 1.f / (denb + EPS_SM);

    // fused node2 epilogue
    float v = acc * inv + b1[lane];
    v = v > 0.f ? v : expm1f(v);   // ELU

    const float4* wp = (const float4*)(W2 + (long)lane * CPH);
    float4 w0 = wp[0], w1 = wp[1];
    float p0 = v * w0.x, p1 = v * w0.y, p2 = v * w0.z, p3 = v * w0.w;
    float p4 = v * w1.x, p5 = v * w1.y, p6 = v * w1.z, p7 = v * w1.w;
#pragma unroll
    for (int m = 1; m < 64; m <<= 1) {
        p0 += __shfl_xor(p0, m);
        p1 += __shfl_xor(p1, m);
        p2 += __shfl_xor(p2, m);
        p3 += __shfl_xor(p3, m);
        p4 += __shfl_xor(p4, m);
        p5 += __shfl_xor(p5, m);
        p6 += __shfl_xor(p6, m);
        p7 += __shfl_xor(p7, m);
    }
    // every lane now holds all 8 column sums
    if (lane == 0) {
        const float4* as = (const float4*)att_src2;
        const float4* ad = (const float4*)att_dst2;
        float4 s0 = as[0], s1 = as[1], d0 = ad[0], d1 = ad[1];
        a_src2[d] = p0 * s0.x + p1 * s0.y + p2 * s0.z + p3 * s0.w +
                    p4 * s1.x + p5 * s1.y + p6 * s1.z + p7 * s1.w;
        a_dst2[d] = p0 * d0.x + p1 * d0.y + p2 * d0.z + p3 * d0.w +
                    p4 * d1.x + p5 * d1.y + p6 * d1.z + p7 * d1.w;
    }
    if (lane < CPH) {
        float ha = (lane & 1) ? p1 : p0, hc = (lane & 1) ? p3 : p2;
        float he = (lane & 1) ? p5 : p4, hg = (lane & 1) ? p7 : p6;
        float hi = (lane & 2) ? hc : ha, hj = (lane & 2) ? hg : he;
        float hv = (lane & 4) ? hj : hi;
        hh[d * CPH + lane] = __float2half(hv);
    }
}

// layer-2 single-pass softmax-aggregation, 8 lanes per node, chunk of 8 edges
__global__ __launch_bounds__(256) void agg2_kernel(
    const int* __restrict__ start, const int* __restrict__ csr_src,
    const float* __restrict__ a_src, const float* __restrict__ a_dst,
    const __half* __restrict__ hh, const float* __restrict__ b2,
    float* __restrict__ out, int N) {
    int c = threadIdx.x & 7;
    int gbase = (threadIdx.x & 63) & ~7;   // 8-lane group base within wave
    long d = (long)blockIdx.x * 32 + (threadIdx.x >> 3);
    if (d >= N) return;
    int begin = (d == 0) ? 0 : start[d - 1];
    int end = start[d];
    float adst = a_dst[d];
    float den = 0.f, acc = 0.f;
    for (int base = begin; base < end; base += 8) {
        int k = base + c;
        int sv = 0;
        float ev = 0.f;
        if (k < end) {
            sv = csr_src[k];
            float v = a_src[sv] + adst;
            v = v >= 0.f ? v : NEG * v;
            ev = __expf(v);
        }
        den += ev;
#pragma unroll
        for (int e = 0; e < 8; ++e) {
            float aE = __shfl(ev, gbase + e);
            int sE = __shfl(sv, gbase + e);
            acc += aE * __half2float(hh[(long)sE * CPH + c]);
        }
    }
    den += __shfl_xor(den, 1);
    den += __shfl_xor(den, 2);
    den += __shfl_xor(den, 4);
    out[d * CPH + c] = acc / (den + EPS_SM) + b2[c];
}

// ---------- launcher ----------

extern "C" void kernel_launch(void* const* d_in, const int* in_sizes, int n_in,
                              void* d_out, int out_size, void* d_ws, size_t ws_size,
                              hipStream_t stream) {
    const float* x = (const float*)d_in[0];
    const void* ei = d_in[1];
    const float* W1 = (const float*)d_in[2];
    const float* att_src1 = (const float*)d_in[3];
    const float* att_dst1 = (const float*)d_in[4];
    const float* b1 = (const float*)d_in[5];
    const float* W2 = (const float*)d_in[6];
    const float* att_src2 = (const float*)d_in[7];
    const float* att_dst2 = (const float*)d_in[8];
    const float* b2 = (const float*)d_in[9];
    float* out = (float*)d_out;

    int N = in_sizes[0] / IN_CH;
    long E = (long)in_sizes[1] / 2;
    long ET = E + N;

    // workspace layout (byte offsets, 256-aligned blocks)
    char* w = (char*)d_ws;
    size_t off = 256;
    auto alloc = [&](size_t bytes) {
        size_t o = off;
        off += (bytes + 255) & ~(size_t)255;
        return (void*)(w + o);
    };
    int* flag = (int*)w;
    __half* h1 = (__half*)alloc((size_t)N * HID * 2);
    float* a_src1 = (float*)alloc((size_t)N * HEADS * 4);
    float* a_dst1 = (float*)alloc((size_t)N * HEADS * 4);
    __half* hh = (__half*)alloc((size_t)N * CPH * 2);
    float* a_src2 = (float*)alloc((size_t)N * 4);
    float* a_dst2 = (float*)alloc((size_t)N * 4);
    int* deg = (int*)alloc((size_t)N * 4);
    int* start = (int*)alloc((size_t)N * 4);
    int* bsum = (int*)alloc(1024 * 4);
    int* csr_src = (int*)alloc((size_t)ET * 4);

    int nb = (N + 255) / 256;
    int ge = (int)((ET + 255) / 256);

    detect_kernel<<<1, 64, 0, stream>>>(ei, E, N, flag);

    gemm1_kernel<<<(N + 3) / 4, 256, 0, stream>>>(x, W1, att_src1, att_dst1,
                                                  h1, a_src1, a_dst1, N);

    zero_deg_kernel<<<nb, 256, 0, stream>>>(deg, N);
    hist_kernel<<<ge, 256, 0, stream>>>(ei, flag, deg, E, N);
    scan1_kernel<<<nb, 256, 0, stream>>>(deg, start, bsum, N);
    scan2_kernel<<<1, 256, 0, stream>>>(bsum, nb);
    scan3_kernel<<<nb, 256, 0, stream>>>(start, bsum, N);
    scatter_kernel<<<ge, 256, 0, stream>>>(ei, flag, start, csr_src, E, N);

    agg1_kernel<<<(N + 3) / 4, 256, 0, stream>>>(start, csr_src, a_src1,
                                                 a_dst1, h1, b1, W2, att_src2,
                                                 att_dst2, hh, a_src2, a_dst2, N);

    agg2_kernel<<<(N + 31) / 32, 256, 0, stream>>>(start, csr_src, a_src2,
                                                   a_dst2, hh, b2, out, N);
}

// Round 5
// 186.219 us; speedup vs baseline: 5.5302x; 1.1653x over previous
//
#include <hip/hip_runtime.h>
#include <hip/hip_fp16.h>

#define IN_CH 128
#define HID 64
#define HEADS 8
#define CPH 8          // channels per head
#define NEG 0.2f
#define EPS_SM 1e-16f

typedef __attribute__((ext_vector_type(8))) _Float16 f16x8;
typedef __attribute__((ext_vector_type(4))) float f32x4;

// ---------- helpers ----------

// edge fetch tolerant to int32 or int64 storage of edge_index [2, E]
__device__ inline void get_edge(const void* ei, int is64, long E, long e, int N,
                                int& s, int& d) {
    if (e >= E) { s = d = (int)(e - E); return; }   // appended self-loop
    if (is64) {
        const long long* p = (const long long*)ei;
        s = (int)p[e];
        d = (int)p[E + e];
    } else {
        const int* p = (const int*)ei;
        s = p[e];
        d = p[E + e];
    }
}

// ---------- kernels ----------

// Decide whether edge_index is stored as int64 (flag=1) or int32 (flag=0).
__global__ void detect_kernel(const void* ei, long E, int N, int* flag) {
    __shared__ int bad;
    if (threadIdx.x == 0) bad = 0;
    __syncthreads();
    const long long* p = (const long long*)ei;
    int n = (int)min((long)64, E);
    if ((int)threadIdx.x < n) {
        long long v = p[threadIdx.x];
        if (v < 0 || v >= (long long)N) atomicOr(&bad, 1);
    }
    __syncthreads();
    if (threadIdx.x == 0) *flag = bad ? 0 : 1;
}

// h1 = x @ W1 via MFMA 16x16x32 f16. One wave = 16 nodes, all of W1 in regs.
// Layouts (gfx950, 16x16x32): A: row=lane&15, k=(lane>>4)*8+j
//                             B: col=lane&15, k=(lane>>4)*8+j
//                             D: col=lane&15, row=(lane>>4)*4+r
__global__ __launch_bounds__(256) void gemm1_mfma_kernel(
    const float* __restrict__ x, const float* __restrict__ W1,
    __half* __restrict__ h1, int N) {
    int lane = threadIdx.x & 63;
    int wid = threadIdx.x >> 6;
    long m0 = ((long)blockIdx.x * 4 + wid) * 16;
    if (m0 >= N) return;
    int lr = lane & 15;   // A-row / B-col / D-col
    int lg = lane >> 4;   // k-group

    // B fragments: b[s][t] covers k=32s..+31, c=16t..+15
    f16x8 b[4][4];
#pragma unroll
    for (int s = 0; s < 4; ++s)
#pragma unroll
        for (int t = 0; t < 4; ++t) {
            const float* wp = W1 + (long)(32 * s + lg * 8) * HID + 16 * t + lr;
#pragma unroll
            for (int j = 0; j < 8; ++j)
                b[s][t][j] = (_Float16)wp[(long)j * HID];
        }

    f32x4 acc[4] = {{0.f, 0.f, 0.f, 0.f}, {0.f, 0.f, 0.f, 0.f},
                    {0.f, 0.f, 0.f, 0.f}, {0.f, 0.f, 0.f, 0.f}};

    long arow = m0 + lr;
    if (arow >= N) arow = N - 1;   // safe clamp (N%16==0 normally)
#pragma unroll
    for (int s = 0; s < 4; ++s) {
        const float4* ap = (const float4*)(x + arow * IN_CH + 32 * s + lg * 8);
        float4 a0 = ap[0], a1 = ap[1];
        f16x8 af = {(_Float16)a0.x, (_Float16)a0.y, (_Float16)a0.z,
                    (_Float16)a0.w, (_Float16)a1.x, (_Float16)a1.y,
                    (_Float16)a1.z, (_Float16)a1.w};
#pragma unroll
        for (int t = 0; t < 4; ++t)
            acc[t] = __builtin_amdgcn_mfma_f32_16x16x32_f16(af, b[s][t],
                                                            acc[t], 0, 0, 0);
    }

#pragma unroll
    for (int t = 0; t < 4; ++t)
#pragma unroll
        for (int r = 0; r < 4; ++r) {
            long n = m0 + lg * 4 + r;
            if (n < N)
                h1[n * HID + 16 * t + lr] = __float2half(acc[t][r]);
        }
}

// attention dots from h1: one 8-lane dot per (node, head)
__global__ __launch_bounds__(256) void att1_kernel(
    const __half* __restrict__ h1, const float* __restrict__ att_src,
    const float* __restrict__ att_dst, float* __restrict__ a_src,
    float* __restrict__ a_dst, int N) {
    long t = (long)blockIdx.x * 256 + threadIdx.x;
    if (t >= (long)N * HEADS) return;
    int h = (int)(t & 7);
    const __half2* hp = (const __half2*)(h1 + t * CPH);
    float acc_s = 0.f, acc_d = 0.f;
#pragma unroll
    for (int j = 0; j < 4; ++j) {
        float2 f = __half22float2(hp[j]);
        acc_s += f.x * att_src[h * CPH + 2 * j] + f.y * att_src[h * CPH + 2 * j + 1];
        acc_d += f.x * att_dst[h * CPH + 2 * j] + f.y * att_dst[h * CPH + 2 * j + 1];
    }
    a_src[t] = acc_s;
    a_dst[t] = acc_d;
}

__global__ void hist_kernel(const void* ei, const int* flag, int* deg,
                            long E, int N) {
    long e = (long)blockIdx.x * 256 + threadIdx.x;
    if (e >= E + N) return;
    int s, d;
    get_edge(ei, *flag, E, e, N, s, d);
    atomicAdd(&deg[d], 1);
}

// exclusive block scan of deg -> start, block totals -> bsum
__global__ void scan1_kernel(const int* deg, int* start, int* bsum, int N) {
    __shared__ int sh[256];
    int t = threadIdx.x;
    int i = blockIdx.x * 256 + t;
    int v = (i < N) ? deg[i] : 0;
    sh[t] = v;
    __syncthreads();
    for (int o = 1; o < 256; o <<= 1) {
        int x = (t >= o) ? sh[t - o] : 0;
        __syncthreads();
        sh[t] += x;
        __syncthreads();
    }
    if (i < N) start[i] = sh[t] - v;
    if (t == 255) bsum[blockIdx.x] = sh[255];
}

// single-block exclusive scan of bsum (any nb, chunked by 256)
__global__ void scan2_kernel(int* bsum, int nb) {
    __shared__ int sh[256];
    __shared__ int carry;
    int t = threadIdx.x;
    if (t == 0) carry = 0;
    __syncthreads();
    for (int base = 0; base < nb; base += 256) {
        int v = (base + t < nb) ? bsum[base + t] : 0;
        sh[t] = v;
        __syncthreads();
        for (int o = 1; o < 256; o <<= 1) {
            int x = (t >= o) ? sh[t - o] : 0;
            __syncthreads();
            sh[t] += x;
            __syncthreads();
        }
        if (base + t < nb) bsum[base + t] = sh[t] - v + carry;
        __syncthreads();
        if (t == 0) carry += sh[255];
        __syncthreads();
    }
}

__global__ void scan3_kernel(int* start, const int* bsum, int N) {
    int i = blockIdx.x * 256 + threadIdx.x;
    if (i < N) start[i] += bsum[blockIdx.x];
}

// scatter src ids into CSR; start[d] mutates from excl-begin to excl-end
__global__ void scatter_kernel(const void* ei, const int* flag, int* start,
                               int* csr_src, long E, int N) {
    long e = (long)blockIdx.x * 256 + threadIdx.x;
    if (e >= E + N) return;
    int s, d;
    get_edge(ei, *flag, E, e, N, s, d);
    int pos = atomicAdd(&start[d], 1);
    csr_src[pos] = s;
}

// layer-1 single-pass softmax-aggregation + fused layer-2 node prep.
// One wave per node; no max-subtraction (logits O(±6), fp32-safe).
__global__ __launch_bounds__(256) void agg1_kernel(
    const int* __restrict__ start, const int* __restrict__ csr_src,
    const float* __restrict__ a_src, const float* __restrict__ a_dst,
    const __half* __restrict__ h1,
    const float* __restrict__ b1, const float* __restrict__ W2,
    const float* __restrict__ att_src2, const float* __restrict__ att_dst2,
    __half* __restrict__ hh, float* __restrict__ a_src2,
    float* __restrict__ a_dst2, int N) {
    int lane = threadIdx.x & 63;
    long d = (long)blockIdx.x * 4 + (threadIdx.x >> 6);
    if (d >= N) return;
    int begin = (d == 0) ? 0 : start[d - 1];
    int end = start[d];

    int eslot = lane >> 3, h = lane & 7;   // chunk layout
    int hb = lane >> 3;                    // head owning channel `lane`
    float adst = a_dst[d * HEADS + h];

    float den = 0.f, acc = 0.f;
    for (int base = begin; base < end; base += 8) {
        int k = base + eslot;
        int sv = 0;
        float ev = 0.f;
        if (k < end) {
            sv = csr_src[k];
            float v = a_src[(long)sv * HEADS + h] + adst;
            v = v >= 0.f ? v : NEG * v;
            ev = __expf(v);
        }
        den += ev;
#pragma unroll
        for (int e = 0; e < 8; ++e) {
            float aE = __shfl(ev, e * 8 + hb);
            int sE = __shfl(sv, e * 8);
            acc += aE * __half2float(h1[(long)sE * HID + lane]);
        }
    }
    den += __shfl_xor(den, 8);
    den += __shfl_xor(den, 16);
    den += __shfl_xor(den, 32);
    float denb = __shfl(den, hb);
    float inv = 1.f / (denb + EPS_SM);

    // fused node2 epilogue
    float v = acc * inv + b1[lane];
    v = v > 0.f ? v : expm1f(v);   // ELU

    const float4* wp = (const float4*)(W2 + (long)lane * CPH);
    float4 w0 = wp[0], w1 = wp[1];
    float p0 = v * w0.x, p1 = v * w0.y, p2 = v * w0.z, p3 = v * w0.w;
    float p4 = v * w1.x, p5 = v * w1.y, p6 = v * w1.z, p7 = v * w1.w;
#pragma unroll
    for (int m = 1; m < 64; m <<= 1) {
        p0 += __shfl_xor(p0, m);
        p1 += __shfl_xor(p1, m);
        p2 += __shfl_xor(p2, m);
        p3 += __shfl_xor(p3, m);
        p4 += __shfl_xor(p4, m);
        p5 += __shfl_xor(p5, m);
        p6 += __shfl_xor(p6, m);
        p7 += __shfl_xor(p7, m);
    }
    if (lane == 0) {
        const float4* as = (const float4*)att_src2;
        const float4* ad = (const float4*)att_dst2;
        float4 s0 = as[0], s1 = as[1], d0 = ad[0], d1 = ad[1];
        a_src2[d] = p0 * s0.x + p1 * s0.y + p2 * s0.z + p3 * s0.w +
                    p4 * s1.x + p5 * s1.y + p6 * s1.z + p7 * s1.w;
        a_dst2[d] = p0 * d0.x + p1 * d0.y + p2 * d0.z + p3 * d0.w +
                    p4 * d1.x + p5 * d1.y + p6 * d1.z + p7 * d1.w;
    }
    if (lane < CPH) {
        float ha = (lane & 1) ? p1 : p0, hc = (lane & 1) ? p3 : p2;
        float he = (lane & 1) ? p5 : p4, hg = (lane & 1) ? p7 : p6;
        float hi = (lane & 2) ? hc : ha, hj = (lane & 2) ? hg : he;
        float hv = (lane & 4) ? hj : hi;
        hh[d * CPH + lane] = __float2half(hv);
    }
}

// layer-2 single-pass softmax-aggregation, 8 lanes per node, chunk of 8 edges
__global__ __launch_bounds__(256) void agg2_kernel(
    const int* __restrict__ start, const int* __restrict__ csr_src,
    const float* __restrict__ a_src, const float* __restrict__ a_dst,
    const __half* __restrict__ hh, const float* __restrict__ b2,
    float* __restrict__ out, int N) {
    int c = threadIdx.x & 7;
    int gbase = (threadIdx.x & 63) & ~7;   // 8-lane group base within wave
    long d = (long)blockIdx.x * 32 + (threadIdx.x >> 3);
    if (d >= N) return;
    int begin = (d == 0) ? 0 : start[d - 1];
    int end = start[d];
    float adst = a_dst[d];
    float den = 0.f, acc = 0.f;
    for (int base = begin; base < end; base += 8) {
        int k = base + c;
        int sv = 0;
        float ev = 0.f;
        if (k < end) {
            sv = csr_src[k];
            float v = a_src[sv] + adst;
            v = v >= 0.f ? v : NEG * v;
            ev = __expf(v);
        }
        den += ev;
#pragma unroll
        for (int e = 0; e < 8; ++e) {
            float aE = __shfl(ev, gbase + e);
            int sE = __shfl(sv, gbase + e);
            acc += aE * __half2float(hh[(long)sE * CPH + c]);
        }
    }
    den += __shfl_xor(den, 1);
    den += __shfl_xor(den, 2);
    den += __shfl_xor(den, 4);
    out[d * CPH + c] = acc / (den + EPS_SM) + b2[c];
}

// ---------- launcher ----------

extern "C" void kernel_launch(void* const* d_in, const int* in_sizes, int n_in,
                              void* d_out, int out_size, void* d_ws, size_t ws_size,
                              hipStream_t stream) {
    const float* x = (const float*)d_in[0];
    const void* ei = d_in[1];
    const float* W1 = (const float*)d_in[2];
    const float* att_src1 = (const float*)d_in[3];
    const float* att_dst1 = (const float*)d_in[4];
    const float* b1 = (const float*)d_in[5];
    const float* W2 = (const float*)d_in[6];
    const float* att_src2 = (const float*)d_in[7];
    const float* att_dst2 = (const float*)d_in[8];
    const float* b2 = (const float*)d_in[9];
    float* out = (float*)d_out;

    int N = in_sizes[0] / IN_CH;
    long E = (long)in_sizes[1] / 2;
    long ET = E + N;

    // workspace layout (byte offsets, 256-aligned blocks)
    char* w = (char*)d_ws;
    size_t off = 256;
    auto alloc = [&](size_t bytes) {
        size_t o = off;
        off += (bytes + 255) & ~(size_t)255;
        return (void*)(w + o);
    };
    int* flag = (int*)w;
    __half* h1 = (__half*)alloc((size_t)N * HID * 2);
    float* a_src1 = (float*)alloc((size_t)N * HEADS * 4);
    float* a_dst1 = (float*)alloc((size_t)N * HEADS * 4);
    __half* hh = (__half*)alloc((size_t)N * CPH * 2);
    float* a_src2 = (float*)alloc((size_t)N * 4);
    float* a_dst2 = (float*)alloc((size_t)N * 4);
    int* deg = (int*)alloc((size_t)N * 4);
    int* start = (int*)alloc((size_t)N * 4);
    int* bsum = (int*)alloc(1024 * 4);
    int* csr_src = (int*)alloc((size_t)ET * 4);

    int nb = (N + 255) / 256;
    int ge = (int)((ET + 255) / 256);

    detect_kernel<<<1, 64, 0, stream>>>(ei, E, N, flag);

    gemm1_mfma_kernel<<<(N + 63) / 64, 256, 0, stream>>>(x, W1, h1, N);
    att1_kernel<<<(int)(((long)N * HEADS + 255) / 256), 256, 0, stream>>>(
        h1, att_src1, att_dst1, a_src1, a_dst1, N);

    hipMemsetAsync(deg, 0, (size_t)N * 4, stream);
    hist_kernel<<<ge, 256, 0, stream>>>(ei, flag, deg, E, N);
    scan1_kernel<<<nb, 256, 0, stream>>>(deg, start, bsum, N);
    scan2_kernel<<<1, 256, 0, stream>>>(bsum, nb);
    scan3_kernel<<<nb, 256, 0, stream>>>(start, bsum, N);
    scatter_kernel<<<ge, 256, 0, stream>>>(ei, flag, start, csr_src, E, N);

    agg1_kernel<<<(N + 3) / 4, 256, 0, stream>>>(start, csr_src, a_src1,
                                                 a_dst1, h1, b1, W2, att_src2,
                                                 att_dst2, hh, a_src2, a_dst2, N);

    agg2_kernel<<<(N + 31) / 32, 256, 0, stream>>>(start, csr_src, a_src2,
                                                   a_dst2, hh, b2, out, N);
}

// Round 6
// 167.118 us; speedup vs baseline: 6.1622x; 1.1143x over previous
//
#include <hip/hip_runtime.h>
#include <hip/hip_fp16.h>

#define IN_CH 128
#define HID 64
#define HEADS 8
#define CPH 8          // channels per head
#define NEG 0.2f
#define EPS_SM 1e-16f

typedef __attribute__((ext_vector_type(8))) _Float16 f16x8;
typedef __attribute__((ext_vector_type(4))) float f32x4;

// ---------- helpers ----------

// edge fetch tolerant to int32 or int64 storage of edge_index [2, E]
__device__ inline void get_edge(const void* ei, int is64, long E, long e, int N,
                                int& s, int& d) {
    if (e >= E) { s = d = (int)(e - E); return; }   // appended self-loop
    if (is64) {
        const long long* p = (const long long*)ei;
        s = (int)p[e];
        d = (int)p[E + e];
    } else {
        const int* p = (const int*)ei;
        s = p[e];
        d = p[E + e];
    }
}

// ---------- kernels ----------

// Decide whether edge_index is stored as int64 (flag=1) or int32 (flag=0).
__global__ void detect_kernel(const void* ei, long E, int N, int* flag) {
    __shared__ int bad;
    if (threadIdx.x == 0) bad = 0;
    __syncthreads();
    const long long* p = (const long long*)ei;
    int n = (int)min((long)64, E);
    if ((int)threadIdx.x < n) {
        long long v = p[threadIdx.x];
        if (v < 0 || v >= (long long)N) atomicOr(&bad, 1);
    }
    __syncthreads();
    if (threadIdx.x == 0) *flag = bad ? 0 : 1;
}

// h1 = x @ W1 via MFMA 16x16x32 f16, with fused attention-dot epilogue.
// Layouts (gfx950, 16x16x32): A: row=lane&15, k=(lane>>4)*8+j
//                             B: col=lane&15, k=(lane>>4)*8+j
//                             D: col=lane&15, row=(lane>>4)*4+r
__global__ __launch_bounds__(256) void gemm1_mfma_kernel(
    const float* __restrict__ x, const float* __restrict__ W1,
    const float* __restrict__ att_src, const float* __restrict__ att_dst,
    __half* __restrict__ h1, float* __restrict__ a_src,
    float* __restrict__ a_dst, int N) {
    int lane = threadIdx.x & 63;
    int wid = threadIdx.x >> 6;
    long m0 = ((long)blockIdx.x * 4 + wid) * 16;
    if (m0 >= N) return;
    int lr = lane & 15;   // A-row / B-col / D-col
    int lg = lane >> 4;   // k-group

    // B fragments: b[s][t] covers k=32s..+31, c=16t..+15
    f16x8 b[4][4];
#pragma unroll
    for (int s = 0; s < 4; ++s)
#pragma unroll
        for (int t = 0; t < 4; ++t) {
            const float* wp = W1 + (long)(32 * s + lg * 8) * HID + 16 * t + lr;
#pragma unroll
            for (int j = 0; j < 8; ++j)
                b[s][t][j] = (_Float16)wp[(long)j * HID];
        }

    f32x4 acc[4] = {{0.f, 0.f, 0.f, 0.f}, {0.f, 0.f, 0.f, 0.f},
                    {0.f, 0.f, 0.f, 0.f}, {0.f, 0.f, 0.f, 0.f}};

    long arow = m0 + lr;
    if (arow >= N) arow = N - 1;
#pragma unroll
    for (int s = 0; s < 4; ++s) {
        const float4* ap = (const float4*)(x + arow * IN_CH + 32 * s + lg * 8);
        float4 a0 = ap[0], a1 = ap[1];
        f16x8 af = {(_Float16)a0.x, (_Float16)a0.y, (_Float16)a0.z,
                    (_Float16)a0.w, (_Float16)a1.x, (_Float16)a1.y,
                    (_Float16)a1.z, (_Float16)a1.w};
#pragma unroll
        for (int t = 0; t < 4; ++t)
            acc[t] = __builtin_amdgcn_mfma_f32_16x16x32_f16(af, b[s][t],
                                                            acc[t], 0, 0, 0);
    }

    // store h1 (fp16)
#pragma unroll
    for (int t = 0; t < 4; ++t)
#pragma unroll
        for (int r = 0; r < 4; ++r) {
            long n = m0 + lg * 4 + r;
            if (n < N)
                h1[n * HID + 16 * t + lr] = __float2half(acc[t][r]);
        }

    // fused attention dots. Channel c = 16t+lr: head ht = 2t+(lr>>3), j = lr&7.
    // Reduce the 8 channels of a head over lanes via xor 1,2,4 (lr bits 0..2).
#pragma unroll
    for (int t = 0; t < 4; ++t) {
        int ht = 2 * t + (lr >> 3);
        float ws = att_src[ht * CPH + (lr & 7)];
        float wd = att_dst[ht * CPH + (lr & 7)];
#pragma unroll
        for (int r = 0; r < 4; ++r) {
            float ps = acc[t][r] * ws;
            float pd = acc[t][r] * wd;
            ps += __shfl_xor(ps, 1);
            ps += __shfl_xor(ps, 2);
            ps += __shfl_xor(ps, 4);
            pd += __shfl_xor(pd, 1);
            pd += __shfl_xor(pd, 2);
            pd += __shfl_xor(pd, 4);
            long n = m0 + lg * 4 + r;
            if ((lr & 7) == 0 && n < N) {
                a_src[n * HEADS + ht] = ps;
                a_dst[n * HEADS + ht] = pd;
            }
        }
    }
}

__global__ void hist_kernel(const void* ei, const int* flag, int* deg,
                            long E, int N) {
    long e = (long)blockIdx.x * 256 + threadIdx.x;
    if (e >= E + N) return;
    int s, d;
    get_edge(ei, *flag, E, e, N, s, d);
    atomicAdd(&deg[d], 1);
}

// exclusive block scan of deg -> start, block totals -> bsum
__global__ void scan1_kernel(const int* deg, int* start, int* bsum, int N) {
    __shared__ int sh[256];
    int t = threadIdx.x;
    int i = blockIdx.x * 256 + t;
    int v = (i < N) ? deg[i] : 0;
    sh[t] = v;
    __syncthreads();
    for (int o = 1; o < 256; o <<= 1) {
        int x = (t >= o) ? sh[t - o] : 0;
        __syncthreads();
        sh[t] += x;
        __syncthreads();
    }
    if (i < N) start[i] = sh[t] - v;
    if (t == 255) bsum[blockIdx.x] = sh[255];
}

// single-block exclusive scan of bsum (any nb, chunked by 256)
__global__ void scan2_kernel(int* bsum, int nb) {
    __shared__ int sh[256];
    __shared__ int carry;
    int t = threadIdx.x;
    if (t == 0) carry = 0;
    __syncthreads();
    for (int base = 0; base < nb; base += 256) {
        int v = (base + t < nb) ? bsum[base + t] : 0;
        sh[t] = v;
        __syncthreads();
        for (int o = 1; o < 256; o <<= 1) {
            int x = (t >= o) ? sh[t - o] : 0;
            __syncthreads();
            sh[t] += x;
            __syncthreads();
        }
        if (base + t < nb) bsum[base + t] = sh[t] - v + carry;
        __syncthreads();
        if (t == 0) carry += sh[255];
        __syncthreads();
    }
}

__global__ void scan3_kernel(int* start, const int* bsum, int N) {
    int i = blockIdx.x * 256 + threadIdx.x;
    if (i < N) start[i] += bsum[blockIdx.x];
}

// scatter src ids into CSR; start[d] mutates from excl-begin to excl-end
__global__ void scatter_kernel(const void* ei, const int* flag, int* start,
                               int* csr_src, long E, int N) {
    long e = (long)blockIdx.x * 256 + threadIdx.x;
    if (e >= E + N) return;
    int s, d;
    get_edge(ei, *flag, E, e, N, s, d);
    int pos = atomicAdd(&start[d], 1);
    csr_src[pos] = s;
}

// layer-1 single-pass softmax-aggregation + fused layer-2 node prep.
// Two nodes per wave (32 lanes each); lane owns channels 2sl, 2sl+1 (half2).
// Chunk of 4 edges: exp-phase lane layout (within half) = eslot*8 + head.
__global__ __launch_bounds__(256) void agg1_kernel(
    const int* __restrict__ start, const int* __restrict__ csr_src,
    const float* __restrict__ a_src, const float* __restrict__ a_dst,
    const __half* __restrict__ h1,
    const float* __restrict__ b1, const float* __restrict__ W2,
    const float* __restrict__ att_src2, const float* __restrict__ att_dst2,
    __half* __restrict__ hh, float* __restrict__ a_src2,
    float* __restrict__ a_dst2, int N) {
    int lane = threadIdx.x & 63;
    int wid = threadIdx.x >> 6;
    int half = lane >> 5;
    int sl = lane & 31;
    int base32 = half << 5;
    long d = (long)blockIdx.x * 8 + wid * 2 + half;
    bool act = d < N;
    long dd = act ? d : (long)(N - 1);
    int begin = (dd == 0) ? 0 : start[dd - 1];
    int end = start[dd];

    int eslot = sl >> 3, h = sl & 7;   // exp-phase layout
    int hb = sl >> 2;                  // head owning channels 2sl, 2sl+1
    float adst = a_dst[dd * HEADS + h];

    float den = 0.f, accx = 0.f, accy = 0.f;
    for (int base = begin; base < end; base += 4) {
        int k = base + eslot;
        int sv = 0;
        float ev = 0.f;
        if (k < end) {
            sv = csr_src[k];
            float v = a_src[(long)sv * HEADS + h] + adst;
            v = v >= 0.f ? v : NEG * v;
            ev = __expf(v);
        }
        den += ev;
#pragma unroll
        for (int e = 0; e < 4; ++e) {
            float aE = __shfl(ev, base32 + e * 8 + hb);
            int sE = __shfl(sv, base32 + e * 8);
            float2 f = __half22float2(
                *(const __half2*)(h1 + (long)sE * HID + 2 * sl));
            accx += aE * f.x;
            accy += aE * f.y;
        }
    }
    // reduce den over eslots (sl bits 3,4); then fetch head hb's den
    den += __shfl_xor(den, 8);
    den += __shfl_xor(den, 16);
    float denb = __shfl(den, base32 + hb);
    float inv = 1.f / (denb + EPS_SM);

    // fused node2 epilogue: 2 channels per lane
    float v0 = accx * inv + b1[2 * sl];
    float v1 = accy * inv + b1[2 * sl + 1];
    v0 = v0 > 0.f ? v0 : expm1f(v0);
    v1 = v1 > 0.f ? v1 : expm1f(v1);

    const float4* wpa = (const float4*)(W2 + (long)(2 * sl) * CPH);
    const float4* wpb = (const float4*)(W2 + (long)(2 * sl + 1) * CPH);
    float4 wa0 = wpa[0], wa1 = wpa[1], wb0 = wpb[0], wb1 = wpb[1];
    float p0 = v0 * wa0.x + v1 * wb0.x;
    float p1 = v0 * wa0.y + v1 * wb0.y;
    float p2 = v0 * wa0.z + v1 * wb0.z;
    float p3 = v0 * wa0.w + v1 * wb0.w;
    float p4 = v0 * wa1.x + v1 * wb1.x;
    float p5 = v0 * wa1.y + v1 * wb1.y;
    float p6 = v0 * wa1.z + v1 * wb1.z;
    float p7 = v0 * wa1.w + v1 * wb1.w;
#pragma unroll
    for (int m = 1; m < 32; m <<= 1) {
        p0 += __shfl_xor(p0, m);
        p1 += __shfl_xor(p1, m);
        p2 += __shfl_xor(p2, m);
        p3 += __shfl_xor(p3, m);
        p4 += __shfl_xor(p4, m);
        p5 += __shfl_xor(p5, m);
        p6 += __shfl_xor(p6, m);
        p7 += __shfl_xor(p7, m);
    }
    if (act) {
        if (sl == 0) {
            const float4* as = (const float4*)att_src2;
            const float4* ad = (const float4*)att_dst2;
            float4 s0 = as[0], s1 = as[1], d0 = ad[0], d1 = ad[1];
            a_src2[d] = p0 * s0.x + p1 * s0.y + p2 * s0.z + p3 * s0.w +
                        p4 * s1.x + p5 * s1.y + p6 * s1.z + p7 * s1.w;
            a_dst2[d] = p0 * d0.x + p1 * d0.y + p2 * d0.z + p3 * d0.w +
                        p4 * d1.x + p5 * d1.y + p6 * d1.z + p7 * d1.w;
        }
        if (sl < CPH) {
            float ha = (sl & 1) ? p1 : p0, hc = (sl & 1) ? p3 : p2;
            float he = (sl & 1) ? p5 : p4, hg = (sl & 1) ? p7 : p6;
            float hi = (sl & 2) ? hc : ha, hj = (sl & 2) ? hg : he;
            float hv = (sl & 4) ? hj : hi;
            hh[d * CPH + sl] = __float2half(hv);
        }
    }
}

// layer-2 single-pass softmax-aggregation, 8 lanes per node, chunk of 8 edges
__global__ __launch_bounds__(256) void agg2_kernel(
    const int* __restrict__ start, const int* __restrict__ csr_src,
    const float* __restrict__ a_src, const float* __restrict__ a_dst,
    const __half* __restrict__ hh, const float* __restrict__ b2,
    float* __restrict__ out, int N) {
    int c = threadIdx.x & 7;
    int gbase = (threadIdx.x & 63) & ~7;   // 8-lane group base within wave
    long d = (long)blockIdx.x * 32 + (threadIdx.x >> 3);
    if (d >= N) return;
    int begin = (d == 0) ? 0 : start[d - 1];
    int end = start[d];
    float adst = a_dst[d];
    float den = 0.f, acc = 0.f;
    for (int base = begin; base < end; base += 8) {
        int k = base + c;
        int sv = 0;
        float ev = 0.f;
        if (k < end) {
            sv = csr_src[k];
            float v = a_src[sv] + adst;
            v = v >= 0.f ? v : NEG * v;
            ev = __expf(v);
        }
        den += ev;
#pragma unroll
        for (int e = 0; e < 8; ++e) {
            float aE = __shfl(ev, gbase + e);
            int sE = __shfl(sv, gbase + e);
            acc += aE * __half2float(hh[(long)sE * CPH + c]);
        }
    }
    den += __shfl_xor(den, 1);
    den += __shfl_xor(den, 2);
    den += __shfl_xor(den, 4);
    out[d * CPH + c] = acc / (den + EPS_SM) + b2[c];
}

// ---------- launcher ----------

extern "C" void kernel_launch(void* const* d_in, const int* in_sizes, int n_in,
                              void* d_out, int out_size, void* d_ws, size_t ws_size,
                              hipStream_t stream) {
    const float* x = (const float*)d_in[0];
    const void* ei = d_in[1];
    const float* W1 = (const float*)d_in[2];
    const float* att_src1 = (const float*)d_in[3];
    const float* att_dst1 = (const float*)d_in[4];
    const float* b1 = (const float*)d_in[5];
    const float* W2 = (const float*)d_in[6];
    const float* att_src2 = (const float*)d_in[7];
    const float* att_dst2 = (const float*)d_in[8];
    const float* b2 = (const float*)d_in[9];
    float* out = (float*)d_out;

    int N = in_sizes[0] / IN_CH;
    long E = (long)in_sizes[1] / 2;
    long ET = E + N;

    // workspace layout (byte offsets, 256-aligned blocks)
    char* w = (char*)d_ws;
    size_t off = 256;
    auto alloc = [&](size_t bytes) {
        size_t o = off;
        off += (bytes + 255) & ~(size_t)255;
        return (void*)(w + o);
    };
    int* flag = (int*)w;
    __half* h1 = (__half*)alloc((size_t)N * HID * 2);
    float* a_src1 = (float*)alloc((size_t)N * HEADS * 4);
    float* a_dst1 = (float*)alloc((size_t)N * HEADS * 4);
    __half* hh = (__half*)alloc((size_t)N * CPH * 2);
    float* a_src2 = (float*)alloc((size_t)N * 4);
    float* a_dst2 = (float*)alloc((size_t)N * 4);
    int* deg = (int*)alloc((size_t)N * 4);
    int* start = (int*)alloc((size_t)N * 4);
    int* bsum = (int*)alloc(1024 * 4);
    int* csr_src = (int*)alloc((size_t)ET * 4);

    int nb = (N + 255) / 256;
    int ge = (int)((ET + 255) / 256);

    detect_kernel<<<1, 64, 0, stream>>>(ei, E, N, flag);

    gemm1_mfma_kernel<<<(N + 63) / 64, 256, 0, stream>>>(
        x, W1, att_src1, att_dst1, h1, a_src1, a_dst1, N);

    hipMemsetAsync(deg, 0, (size_t)N * 4, stream);
    hist_kernel<<<ge, 256, 0, stream>>>(ei, flag, deg, E, N);
    scan1_kernel<<<nb, 256, 0, stream>>>(deg, start, bsum, N);
    scan2_kernel<<<1, 256, 0, stream>>>(bsum, nb);
    scan3_kernel<<<nb, 256, 0, stream>>>(start, bsum, N);
    scatter_kernel<<<ge, 256, 0, stream>>>(ei, flag, start, csr_src, E, N);

    agg1_kernel<<<(N + 7) / 8, 256, 0, stream>>>(start, csr_src, a_src1,
                                                 a_dst1, h1, b1, W2, att_src2,
                                                 att_dst2, hh, a_src2, a_dst2, N);

    agg2_kernel<<<(N + 31) / 32, 256, 0, stream>>>(start, csr_src, a_src2,
                                                   a_dst2, hh, b2, out, N);
}

// Round 7
// 109.819 us; speedup vs baseline: 9.3775x; 1.5218x over previous
//
#include <hip/hip_runtime.h>
#include <hip/hip_fp16.h>

#define IN_CH 128
#define HID 64
#define HEADS 8
#define CPH 8          // channels per head
#define NEG 0.2f
#define EPS_SM 1e-16f
#define NB 256         // dst buckets (bucket = dst >> 8); requires N <= 65536
#define CHB 4096       // edges per block in bucketize pass (16/thread)

typedef __attribute__((ext_vector_type(8))) _Float16 f16x8;
typedef __attribute__((ext_vector_type(4))) float f32x4;

// ---------- helpers ----------

// edge fetch tolerant to int32 or int64 storage of edge_index [2, E]
__device__ inline void get_edge(const void* ei, int is64, long E, long e, int N,
                                int& s, int& d) {
    if (e >= E) { s = d = (int)(e - E); return; }   // appended self-loop
    if (is64) {
        const long long* p = (const long long*)ei;
        s = (int)p[e];
        d = (int)p[E + e];
    } else {
        const int* p = (const int*)ei;
        s = p[e];
        d = p[E + e];
    }
}

// ---------- kernels ----------

// Decide whether edge_index is stored as int64 (flag=1) or int32 (flag=0).
__global__ void detect_kernel(const void* ei, long E, int N, int* flag) {
    __shared__ int bad;
    if (threadIdx.x == 0) bad = 0;
    __syncthreads();
    const long long* p = (const long long*)ei;
    int n = (int)min((long)64, E);
    if ((int)threadIdx.x < n) {
        long long v = p[threadIdx.x];
        if (v < 0 || v >= (long long)N) atomicOr(&bad, 1);
    }
    __syncthreads();
    if (threadIdx.x == 0) *flag = bad ? 0 : 1;
}

// h1 = x @ W1 via MFMA 16x16x32 f16, with fused attention-dot epilogue.
__global__ __launch_bounds__(256) void gemm1_mfma_kernel(
    const float* __restrict__ x, const float* __restrict__ W1,
    const float* __restrict__ att_src, const float* __restrict__ att_dst,
    __half* __restrict__ h1, float* __restrict__ a_src,
    float* __restrict__ a_dst, int N) {
    int lane = threadIdx.x & 63;
    int wid = threadIdx.x >> 6;
    long m0 = ((long)blockIdx.x * 4 + wid) * 16;
    if (m0 >= N) return;
    int lr = lane & 15;   // A-row / B-col / D-col
    int lg = lane >> 4;   // k-group

    f16x8 b[4][4];
#pragma unroll
    for (int s = 0; s < 4; ++s)
#pragma unroll
        for (int t = 0; t < 4; ++t) {
            const float* wp = W1 + (long)(32 * s + lg * 8) * HID + 16 * t + lr;
#pragma unroll
            for (int j = 0; j < 8; ++j)
                b[s][t][j] = (_Float16)wp[(long)j * HID];
        }

    f32x4 acc[4] = {{0.f, 0.f, 0.f, 0.f}, {0.f, 0.f, 0.f, 0.f},
                    {0.f, 0.f, 0.f, 0.f}, {0.f, 0.f, 0.f, 0.f}};

    long arow = m0 + lr;
    if (arow >= N) arow = N - 1;
#pragma unroll
    for (int s = 0; s < 4; ++s) {
        const float4* ap = (const float4*)(x + arow * IN_CH + 32 * s + lg * 8);
        float4 a0 = ap[0], a1 = ap[1];
        f16x8 af = {(_Float16)a0.x, (_Float16)a0.y, (_Float16)a0.z,
                    (_Float16)a0.w, (_Float16)a1.x, (_Float16)a1.y,
                    (_Float16)a1.z, (_Float16)a1.w};
#pragma unroll
        for (int t = 0; t < 4; ++t)
            acc[t] = __builtin_amdgcn_mfma_f32_16x16x32_f16(af, b[s][t],
                                                            acc[t], 0, 0, 0);
    }

#pragma unroll
    for (int t = 0; t < 4; ++t)
#pragma unroll
        for (int r = 0; r < 4; ++r) {
            long n = m0 + lg * 4 + r;
            if (n < N)
                h1[n * HID + 16 * t + lr] = __float2half(acc[t][r]);
        }

    // fused attention dots: channel c=16t+lr -> head 2t+(lr>>3), j=lr&7
#pragma unroll
    for (int t = 0; t < 4; ++t) {
        int ht = 2 * t + (lr >> 3);
        float ws = att_src[ht * CPH + (lr & 7)];
        float wd = att_dst[ht * CPH + (lr & 7)];
#pragma unroll
        for (int r = 0; r < 4; ++r) {
            float ps = acc[t][r] * ws;
            float pd = acc[t][r] * wd;
            ps += __shfl_xor(ps, 1);
            ps += __shfl_xor(ps, 2);
            ps += __shfl_xor(ps, 4);
            pd += __shfl_xor(pd, 1);
            pd += __shfl_xor(pd, 2);
            pd += __shfl_xor(pd, 4);
            long n = m0 + lg * 4 + r;
            if ((lr & 7) == 0 && n < N) {
                a_src[n * HEADS + ht] = ps;
                a_dst[n * HEADS + ht] = pd;
            }
        }
    }
}

// Pass A: coarse bucket histogram (bucket = dst >> 8)
__global__ __launch_bounds__(256) void bucketA_kernel(
    const void* ei, const int* flag, int* bucket_cnt, long E, int N) {
    __shared__ int h[NB];
    h[threadIdx.x] = 0;
    __syncthreads();
    int is64 = *flag;
    long ET = E + N;
    long stride = (long)gridDim.x * 256;
    for (long e = (long)blockIdx.x * 256 + threadIdx.x; e < ET; e += stride) {
        int d;
        if (e >= E) d = (int)(e - E);
        else if (is64) d = (int)((const long long*)ei)[E + e];
        else d = ((const int*)ei)[E + e];
        atomicAdd(&h[d >> 8], 1);
    }
    __syncthreads();
    if (h[threadIdx.x]) atomicAdd(&bucket_cnt[threadIdx.x], h[threadIdx.x]);
}

// exclusive scan of the 256 bucket counts; also init cursors
__global__ void bucket_scan_kernel(const int* bucket_cnt, int* bucket_base,
                                   int* bucket_cur) {
    __shared__ int sh[NB];
    int t = threadIdx.x;
    int v = bucket_cnt[t];
    sh[t] = v;
    __syncthreads();
    for (int o = 1; o < NB; o <<= 1) {
        int x = (t >= o) ? sh[t - o] : 0;
        __syncthreads();
        sh[t] += x;
        __syncthreads();
    }
    int excl = sh[t] - v;
    bucket_base[t] = excl;
    bucket_cur[t] = excl;
    if (t == NB - 1) bucket_base[NB] = sh[t];
}

// Pass B: bucketize edges into tmp as packed (dst<<16 | src) records.
// Block-local LDS histogram -> one global reservation per bucket -> runs of
// ~CHB/NB consecutive records per bucket region (write-locality friendly).
__global__ __launch_bounds__(256) void bucketB_kernel(
    const void* ei, const int* flag, int* bucket_cur, unsigned* tmp,
    long E, int N) {
    __shared__ int h[NB];
    h[threadIdx.x] = 0;
    __syncthreads();
    int is64 = *flag;
    long ET = E + N;
    long base_e = (long)blockIdx.x * CHB;
    unsigned rec[CHB / 256];
#pragma unroll
    for (int i = 0; i < CHB / 256; ++i) {
        long e = base_e + (long)i * 256 + threadIdx.x;
        unsigned r = 0xFFFFFFFFu;
        if (e < ET) {
            int s, d;
            get_edge(ei, is64, E, e, N, s, d);
            r = ((unsigned)d << 16) | (unsigned)s;
            atomicAdd(&h[d >> 8], 1);
        }
        rec[i] = r;
    }
    __syncthreads();
    int c = h[threadIdx.x];
    int gb = 0;
    if (c > 0) gb = atomicAdd(&bucket_cur[threadIdx.x], c);
    h[threadIdx.x] = gb;   // repurpose as global cursor
    __syncthreads();
#pragma unroll
    for (int i = 0; i < CHB / 256; ++i) {
        unsigned r = rec[i];
        if (r != 0xFFFFFFFFu) {
            int pos = atomicAdd(&h[r >> 24], 1);
            tmp[pos] = r;
        }
    }
}

// Pass C: one block per bucket. Local per-dst count + scan -> start[] and
// final csr scatter, all writes confined to the bucket's ~17KB region.
__global__ __launch_bounds__(256) void bucketC_kernel(
    const unsigned* __restrict__ tmp, const int* __restrict__ bucket_base,
    int* __restrict__ start, unsigned short* __restrict__ csr_src, int N) {
    __shared__ int cnt[NB], cur[NB];
    int b = blockIdx.x;
    int base = bucket_base[b], endb = bucket_base[b + 1];
    int n = endb - base;
    cnt[threadIdx.x] = 0;
    __syncthreads();
    for (int i = threadIdx.x; i < n; i += 256)
        atomicAdd(&cnt[(tmp[base + i] >> 16) & 255], 1);
    __syncthreads();
    int v = cnt[threadIdx.x];
    for (int o = 1; o < NB; o <<= 1) {
        int x = (threadIdx.x >= o) ? cnt[threadIdx.x - o] : 0;
        __syncthreads();
        cnt[threadIdx.x] += x;
        __syncthreads();
    }
    int excl = cnt[threadIdx.x] - v;
    cur[threadIdx.x] = base + excl;
    int d = b * NB + threadIdx.x;
    if (d < N) start[d] = base + excl;
    __syncthreads();
    for (int i = threadIdx.x; i < n; i += 256) {
        unsigned r = tmp[base + i];
        int pos = atomicAdd(&cur[(r >> 16) & 255], 1);
        csr_src[pos] = (unsigned short)(r & 0xFFFFu);
    }
}

// layer-1 single-pass softmax-aggregation + fused layer-2 node prep.
// Two nodes per wave (32 lanes each); lane owns channels 2sl, 2sl+1 (half2).
__global__ __launch_bounds__(256) void agg1_kernel(
    const int* __restrict__ start, const unsigned short* __restrict__ csr_src,
    const float* __restrict__ a_src, const float* __restrict__ a_dst,
    const __half* __restrict__ h1,
    const float* __restrict__ b1, const float* __restrict__ W2,
    const float* __restrict__ att_src2, const float* __restrict__ att_dst2,
    __half* __restrict__ hh, float* __restrict__ a_src2,
    float* __restrict__ a_dst2, int N, int ET) {
    int lane = threadIdx.x & 63;
    int wid = threadIdx.x >> 6;
    int half = lane >> 5;
    int sl = lane & 31;
    int base32 = half << 5;
    long d = (long)blockIdx.x * 8 + wid * 2 + half;
    bool act = d < N;
    long dd = act ? d : (long)(N - 1);
    int begin = start[dd];
    int end = (dd == N - 1) ? ET : start[dd + 1];

    int eslot = sl >> 3, h = sl & 7;   // exp-phase layout
    int hb = sl >> 2;                  // head owning channels 2sl, 2sl+1
    float adst = a_dst[dd * HEADS + h];

    float den = 0.f, accx = 0.f, accy = 0.f;
    for (int base = begin; base < end; base += 4) {
        int k = base + eslot;
        int sv = 0;
        float ev = 0.f;
        if (k < end) {
            sv = csr_src[k];
            float v = a_src[(long)sv * HEADS + h] + adst;
            v = v >= 0.f ? v : NEG * v;
            ev = __expf(v);
        }
        den += ev;
#pragma unroll
        for (int e = 0; e < 4; ++e) {
            float aE = __shfl(ev, base32 + e * 8 + hb);
            int sE = __shfl(sv, base32 + e * 8);
            float2 f = __half22float2(
                *(const __half2*)(h1 + (long)sE * HID + 2 * sl));
            accx += aE * f.x;
            accy += aE * f.y;
        }
    }
    den += __shfl_xor(den, 8);
    den += __shfl_xor(den, 16);
    float denb = __shfl(den, base32 + hb);
    float inv = 1.f / (denb + EPS_SM);

    // fused node2 epilogue: 2 channels per lane
    float v0 = accx * inv + b1[2 * sl];
    float v1 = accy * inv + b1[2 * sl + 1];
    v0 = v0 > 0.f ? v0 : expm1f(v0);
    v1 = v1 > 0.f ? v1 : expm1f(v1);

    const float4* wpa = (const float4*)(W2 + (long)(2 * sl) * CPH);
    const float4* wpb = (const float4*)(W2 + (long)(2 * sl + 1) * CPH);
    float4 wa0 = wpa[0], wa1 = wpa[1], wb0 = wpb[0], wb1 = wpb[1];
    float p0 = v0 * wa0.x + v1 * wb0.x;
    float p1 = v0 * wa0.y + v1 * wb0.y;
    float p2 = v0 * wa0.z + v1 * wb0.z;
    float p3 = v0 * wa0.w + v1 * wb0.w;
    float p4 = v0 * wa1.x + v1 * wb1.x;
    float p5 = v0 * wa1.y + v1 * wb1.y;
    float p6 = v0 * wa1.z + v1 * wb1.z;
    float p7 = v0 * wa1.w + v1 * wb1.w;
#pragma unroll
    for (int m = 1; m < 32; m <<= 1) {
        p0 += __shfl_xor(p0, m);
        p1 += __shfl_xor(p1, m);
        p2 += __shfl_xor(p2, m);
        p3 += __shfl_xor(p3, m);
        p4 += __shfl_xor(p4, m);
        p5 += __shfl_xor(p5, m);
        p6 += __shfl_xor(p6, m);
        p7 += __shfl_xor(p7, m);
    }
    if (act) {
        if (sl == 0) {
            const float4* as = (const float4*)att_src2;
            const float4* ad = (const float4*)att_dst2;
            float4 s0 = as[0], s1 = as[1], d0 = ad[0], d1 = ad[1];
            a_src2[d] = p0 * s0.x + p1 * s0.y + p2 * s0.z + p3 * s0.w +
                        p4 * s1.x + p5 * s1.y + p6 * s1.z + p7 * s1.w;
            a_dst2[d] = p0 * d0.x + p1 * d0.y + p2 * d0.z + p3 * d0.w +
                        p4 * d1.x + p5 * d1.y + p6 * d1.z + p7 * d1.w;
        }
        if (sl < CPH) {
            float ha = (sl & 1) ? p1 : p0, hc = (sl & 1) ? p3 : p2;
            float he = (sl & 1) ? p5 : p4, hg = (sl & 1) ? p7 : p6;
            float hi = (sl & 2) ? hc : ha, hj = (sl & 2) ? hg : he;
            float hv = (sl & 4) ? hj : hi;
            hh[d * CPH + sl] = __float2half(hv);
        }
    }
}

// layer-2 single-pass softmax-aggregation, 8 lanes per node, chunk of 8 edges
__global__ __launch_bounds__(256) void agg2_kernel(
    const int* __restrict__ start, const unsigned short* __restrict__ csr_src,
    const float* __restrict__ a_src, const float* __restrict__ a_dst,
    const __half* __restrict__ hh, const float* __restrict__ b2,
    float* __restrict__ out, int N, int ET) {
    int c = threadIdx.x & 7;
    int gbase = (threadIdx.x & 63) & ~7;   // 8-lane group base within wave
    long d = (long)blockIdx.x * 32 + (threadIdx.x >> 3);
    if (d >= N) return;
    int begin = start[d];
    int end = (d == N - 1) ? ET : start[d + 1];
    float adst = a_dst[d];
    float den = 0.f, acc = 0.f;
    for (int base = begin; base < end; base += 8) {
        int k = base + c;
        int sv = 0;
        float ev = 0.f;
        if (k < end) {
            sv = csr_src[k];
            float v = a_src[sv] + adst;
            v = v >= 0.f ? v : NEG * v;
            ev = __expf(v);
        }
        den += ev;
#pragma unroll
        for (int e = 0; e < 8; ++e) {
            float aE = __shfl(ev, gbase + e);
            int sE = __shfl(sv, gbase + e);
            acc += aE * __half2float(hh[(long)sE * CPH + c]);
        }
    }
    den += __shfl_xor(den, 1);
    den += __shfl_xor(den, 2);
    den += __shfl_xor(den, 4);
    out[d * CPH + c] = acc / (den + EPS_SM) + b2[c];
}

// ---------- launcher ----------

extern "C" void kernel_launch(void* const* d_in, const int* in_sizes, int n_in,
                              void* d_out, int out_size, void* d_ws, size_t ws_size,
                              hipStream_t stream) {
    const float* x = (const float*)d_in[0];
    const void* ei = d_in[1];
    const float* W1 = (const float*)d_in[2];
    const float* att_src1 = (const float*)d_in[3];
    const float* att_dst1 = (const float*)d_in[4];
    const float* b1 = (const float*)d_in[5];
    const float* W2 = (const float*)d_in[6];
    const float* att_src2 = (const float*)d_in[7];
    const float* att_dst2 = (const float*)d_in[8];
    const float* b2 = (const float*)d_in[9];
    float* out = (float*)d_out;

    int N = in_sizes[0] / IN_CH;
    long E = (long)in_sizes[1] / 2;
    long ET = E + N;

    // workspace layout (byte offsets, 256-aligned blocks)
    char* w = (char*)d_ws;
    size_t off = 256;
    auto alloc = [&](size_t bytes) {
        size_t o = off;
        off += (bytes + 255) & ~(size_t)255;
        return (void*)(w + o);
    };
    int* flag = (int*)w;
    __half* h1 = (__half*)alloc((size_t)N * HID * 2);
    float* a_src1 = (float*)alloc((size_t)N * HEADS * 4);
    float* a_dst1 = (float*)alloc((size_t)N * HEADS * 4);
    __half* hh = (__half*)alloc((size_t)N * CPH * 2);
    float* a_src2 = (float*)alloc((size_t)N * 4);
    float* a_dst2 = (float*)alloc((size_t)N * 4);
    int* start = (int*)alloc((size_t)N * 4);
    int* bucket_cnt = (int*)alloc(NB * 4);
    int* bucket_base = (int*)alloc((NB + 1) * 4);
    int* bucket_cur = (int*)alloc(NB * 4);
    unsigned* tmp = (unsigned*)alloc((size_t)ET * 4);
    unsigned short* csr_src = (unsigned short*)alloc((size_t)ET * 2);

    detect_kernel<<<1, 64, 0, stream>>>(ei, E, N, flag);

    gemm1_mfma_kernel<<<(N + 63) / 64, 256, 0, stream>>>(
        x, W1, att_src1, att_dst1, h1, a_src1, a_dst1, N);

    hipMemsetAsync(bucket_cnt, 0, NB * 4, stream);
    bucketA_kernel<<<256, 256, 0, stream>>>(ei, flag, bucket_cnt, E, N);
    bucket_scan_kernel<<<1, NB, 0, stream>>>(bucket_cnt, bucket_base, bucket_cur);
    bucketB_kernel<<<(int)((ET + CHB - 1) / CHB), 256, 0, stream>>>(
        ei, flag, bucket_cur, tmp, E, N);
    bucketC_kernel<<<NB, 256, 0, stream>>>(tmp, bucket_base, start, csr_src, N);

    agg1_kernel<<<(N + 7) / 8, 256, 0, stream>>>(
        start, csr_src, a_src1, a_dst1, h1, b1, W2, att_src2, att_dst2,
        hh, a_src2, a_dst2, N, (int)ET);

    agg2_kernel<<<(N + 31) / 32, 256, 0, stream>>>(
        start, csr_src, a_src2, a_dst2, hh, b2, out, N, (int)ET);
}